// Round 8
// baseline (155.490 us; speedup 1.0000x reference)
//
#include <hip/hip_runtime.h>
#include <math.h>

typedef _Float16 h2 __attribute__((ext_vector_type(2)));
typedef __fp16 hh4 __attribute__((ext_vector_type(4)));
typedef float f4 __attribute__((ext_vector_type(4)));

#define Bsz 16
#define Ssz 1024
#define TOKENS (Bsz * Ssz)   // 16384
#define Dd 64
#define Hh 8

#if __has_builtin(__builtin_amdgcn_exp2f)
  #define EXPFN(x) __builtin_amdgcn_exp2f(x)
  #define SQRT_PRESCALE 0.7141921f     // sqrt((1/sqrt(8)) * log2(e))
#else
  #define EXPFN(x) __expf(x)
  #define SQRT_PRESCALE 0.5946036f     // sqrt(1/sqrt(8))
#endif

#if __has_builtin(__builtin_amdgcn_mfma_f32_16x16x16_f16)
  #define MFMA16(a, b, c) __builtin_amdgcn_mfma_f32_16x16x16_f16(a, b, c, 0, 0, 0)
#else
  #define MFMA16(a, b, c) __builtin_amdgcn_mfma_f32_16x16x16f16(a, b, c, 0, 0, 0)
#endif

__device__ __forceinline__ h2 pkrtz(float a, float b) {
#if __has_builtin(__builtin_amdgcn_cvt_pkrtz)
  return __builtin_bit_cast(h2, __builtin_amdgcn_cvt_pkrtz(a, b));
#else
  h2 r; r.x = (_Float16)a; r.y = (_Float16)b; return r;
#endif
}
__device__ __forceinline__ unsigned int as_u32(h2 v) {
  return __builtin_bit_cast(unsigned int, v);
}
__device__ __forceinline__ hh4 bc4(uint2 u) {
  return __builtin_bit_cast(hh4, u);
}

#if __has_builtin(__builtin_amdgcn_readlane)
__device__ __forceinline__ float rdlane(float v, int l) {
  return __int_as_float(__builtin_amdgcn_readlane(__float_as_int(v), l));
}
#else
__device__ __forceinline__ float rdlane(float v, int l) { return __shfl(v, l, 64); }
#endif

__device__ __forceinline__ float wave_reduce_sum(float v) {
#pragma unroll
  for (int off = 32; off >= 1; off >>= 1) v += __shfl_xor(v, off, 64);
  return v;
}

// quantum head q-vector for one token/head
__device__ __forceinline__ void qheads(const float* __restrict__ xp,
                                       const float* th, float* o) {
  float4 v0 = *(const float4*)(xp);
  float4 v1 = *(const float4*)(xp + 4);
  float c0 = __cosf(v0.x + th[0]), c1 = __cosf(v0.y + th[1]);
  float c2 = __cosf(v0.z + th[2]), c3 = __cosf(v0.w + th[3]);
  float c4 = __cosf(v1.x + th[4]), c5 = __cosf(v1.y + th[5]);
  float c6 = __cosf(v1.z + th[6]), c7 = __cosf(v1.w + th[7]);
  float cp = c0;
  cp *= c1; o[1] = cp; cp *= c2; o[2] = cp; cp *= c3; o[3] = cp;
  cp *= c4; o[4] = cp; cp *= c5; o[5] = cp; cp *= c6; o[6] = cp;
  cp *= c7; o[7] = cp;
  o[0] = c1 * c2 * c3 * c4 * c5 * c6 * c7;
}

// ---------------------------------------------------------------- embed + pos
__global__ __launch_bounds__(256) void embed_kernel(
    const int* __restrict__ tokens, const float* __restrict__ emb,
    float* __restrict__ x) {
  int gid = blockIdx.x * 256 + threadIdx.x;   // 0 .. TOKENS*32-1
  if (gid >= TOKENS * 32) return;
  int d2 = gid & 31;
  int ts = gid >> 5;
  int s  = ts & (Ssz - 1);
  int tok = tokens[ts];
  float freq = __expf((float)(2 * d2) * (-0.14391156831f));
  float ang = (float)s * freq;
  float sn, cs;
  __sincosf(ang, &sn, &cs);
  float2 e2 = *(const float2*)&emb[(size_t)tok * Dd + 2 * d2];
  float2 r;
  r.x = e2.x + sn;
  r.y = e2.y + cs;
  *(float2*)&x[(size_t)ts * Dd + 2 * d2] = r;
}

// ------------------------------------------------- MFMA flash attention
// grid = 128 bh * 8 rowsplits = 1024 blocks, 256 threads (4 waves).
// LDS 32.1 KB -> 4 blocks/CU. S^T tile = mfma(A=keys, B=rows); exp2;
// O^T tile += mfma(A=Q^T (8 real d-rows), B=P^T). D-rows 8-15 are garbage
// and discarded by the g<2 store guard.
__global__ __launch_bounds__(256, 4) void attn_kernel(
    const float* __restrict__ x, const float* __restrict__ theta,
    float* __restrict__ o_out, float* __restrict__ ps_out) {
  __shared__ unsigned int qrs[Ssz * 4 + 2];  // [k][4]: f16x2 pairs, x sqrt(scale); +2 zero pad
  __shared__ unsigned int qtt[8 * 514];      // [d<8][514]: (k,k+1) f16 pairs, unscaled
  int blk = blockIdx.x;
  int bh = blk >> 3, split = blk & 7;
  int b = bh >> 3, h = bh & 7;
  int t = threadIdx.x;

  float th[8];
#pragma unroll
  for (int i = 0; i < 8; i++) th[i] = theta[i];

  const float* xb = x + (size_t)b * Ssz * Dd + h * 8;

  // stage 4 consecutive rows per thread
#pragma unroll
  for (int i = 0; i < 4; i += 2) {
    int k0 = t * 4 + i;
    float oa[8], ob[8];
    qheads(xb + (size_t)k0 * Dd, th, oa);
    qheads(xb + (size_t)(k0 + 1) * Dd, th, ob);
    uint4 wa, wb;
    wa.x = as_u32(pkrtz(oa[0] * SQRT_PRESCALE, oa[1] * SQRT_PRESCALE));
    wa.y = as_u32(pkrtz(oa[2] * SQRT_PRESCALE, oa[3] * SQRT_PRESCALE));
    wa.z = as_u32(pkrtz(oa[4] * SQRT_PRESCALE, oa[5] * SQRT_PRESCALE));
    wa.w = as_u32(pkrtz(oa[6] * SQRT_PRESCALE, oa[7] * SQRT_PRESCALE));
    wb.x = as_u32(pkrtz(ob[0] * SQRT_PRESCALE, ob[1] * SQRT_PRESCALE));
    wb.y = as_u32(pkrtz(ob[2] * SQRT_PRESCALE, ob[3] * SQRT_PRESCALE));
    wb.z = as_u32(pkrtz(ob[4] * SQRT_PRESCALE, ob[5] * SQRT_PRESCALE));
    wb.w = as_u32(pkrtz(ob[6] * SQRT_PRESCALE, ob[7] * SQRT_PRESCALE));
    *(uint4*)&qrs[k0 * 4] = wa;
    *(uint4*)&qrs[(k0 + 1) * 4] = wb;
#pragma unroll
    for (int d = 0; d < 8; d++)
      qtt[d * 514 + (k0 >> 1)] = as_u32(pkrtz(oa[d], ob[d]));  // unscaled
  }
  if (t == 0) { qrs[Ssz * 4] = 0; qrs[Ssz * 4 + 1] = 0; }
  __syncthreads();

  int l = t & 63, w = t >> 6;
  int g = l >> 4, rr = l & 15;
  int rt0 = split * 8 + w * 2;          // this wave's two row-tiles
  int rowA = rt0 * 16 + rr;
  int rowB = rowA + 16;
  uint2 z2; z2.x = 0; z2.y = 0;
  uint2 buA = (g < 2) ? *(const uint2*)&qrs[rowA * 4 + 2 * g] : z2;
  uint2 buB = (g < 2) ? *(const uint2*)&qrs[rowB * 4 + 2 * g] : z2;
  hh4 BrA = bc4(buA), BrB = bc4(buB);
  // A-operand (keys) read: base/stride so lanes g>=2 hit the zero pad
  int aoff  = (g < 2) ? (rr * 4 + 2 * g) : (Ssz * 4);
  int astep = (g < 2) ? 64 : 0;
  int qoff  = (rr & 7) * 514 + 2 * g;   // Q^T read (d-row rr&7)
  f4 zf = {0.f, 0.f, 0.f, 0.f};
  f4 accA = zf, accB = zf;
  float psA = 0.f, psB = 0.f;

#pragma unroll 4
  for (int kt = 0; kt < 64; ++kt) {
    uint2 au = *(const uint2*)&qrs[aoff + kt * astep];
    hh4 Ak = bc4(au);
    f4 sA = MFMA16(Ak, BrA, zf);     // S^T tile: [key 4g+reg][row rr]
    f4 sB = MFMA16(Ak, BrB, zf);
    float pA0 = EXPFN(sA.x), pA1 = EXPFN(sA.y), pA2 = EXPFN(sA.z), pA3 = EXPFN(sA.w);
    float pB0 = EXPFN(sB.x), pB1 = EXPFN(sB.y), pB2 = EXPFN(sB.z), pB3 = EXPFN(sB.w);
    psA += (pA0 + pA1) + (pA2 + pA3);
    psB += (pB0 + pB1) + (pB2 + pB3);
    uint2 pbA, pbB;
    pbA.x = as_u32(pkrtz(pA0, pA1)); pbA.y = as_u32(pkrtz(pA2, pA3));
    pbB.x = as_u32(pkrtz(pB0, pB1)); pbB.y = as_u32(pkrtz(pB2, pB3));
    uint2 qt = *(const uint2*)&qtt[qoff + kt * 8];  // Q^T[d=rr&7][keys kt*16+4g..+3]
    hh4 Aq = bc4(qt);
    accA = MFMA16(Aq, bc4(pbA), accA);   // O^T += Q^T · P^T
    accB = MFMA16(Aq, bc4(pbB), accB);
  }
  psA += __shfl_xor(psA, 16, 64); psA += __shfl_xor(psA, 32, 64);
  psB += __shfl_xor(psB, 16, 64); psB += __shfl_xor(psB, 32, 64);

  size_t tokA = (size_t)b * Ssz + rowA;
  size_t tokB = (size_t)b * Ssz + rowB;
  if (g < 2) {   // lanes 0..31 hold valid d = 4g+reg
    *(f4*)&o_out[tokA * 64 + h * 8 + 4 * g] = accA;
    *(f4*)&o_out[tokB * 64 + h * 8 + 4 * g] = accB;
  }
  if (l < 16) {
    ps_out[tokA * 8 + h] = psA;
    ps_out[tokB * 8 + h] = psB;
  }
}

// ---- fused tail: normalize + combine + LN1 + quantum FFN + LN2 + pooling
// Wc row (64) + W2 row (128) in VGPRs; activations broadcast via readlane.
__global__ __launch_bounds__(256, 2) void tail_kernel(
    float* __restrict__ x, const float* __restrict__ o_out,
    const float* __restrict__ ps_out, const float* __restrict__ Wc,
    const float* __restrict__ g1, const float* __restrict__ bb1,
    const float* __restrict__ g2, const float* __restrict__ bb2,
    const float* __restrict__ fth,
    const float* __restrict__ W1, const float* __restrict__ fb1,
    const float* __restrict__ W2, const float* __restrict__ fb2,
    float* __restrict__ partial, int do_partial) {
  __shared__ float red[4][64];
  int lane = threadIdx.x & 63, w = threadIdx.x >> 6;
  float wc[64];
#pragma unroll
  for (int i = 0; i < 16; i++) {
    float4 v = *(const float4*)&Wc[lane * 64 + i * 4];
    wc[4 * i] = v.x; wc[4 * i + 1] = v.y; wc[4 * i + 2] = v.z; wc[4 * i + 3] = v.w;
  }
  float w2[128];
#pragma unroll
  for (int i = 0; i < 32; i++) {
    float4 v = *(const float4*)&W2[lane * 128 + i * 4];
    w2[4 * i] = v.x; w2[4 * i + 1] = v.y; w2[4 * i + 2] = v.z; w2[4 * i + 3] = v.w;
  }
  float w1a[8], w1b[8];
#pragma unroll
  for (int i = 0; i < 8; i++) {
    w1a[i] = W1[lane * 8 + i];
    w1b[i] = W1[(lane + 64) * 8 + i];
  }
  float fb1a = fb1[lane], fb1b = fb1[lane + 64];
  float g1d = g1[lane], b1d = bb1[lane];
  float g2d = g2[lane], b2d = bb2[lane];
  float fb2d = fb2[lane];
  float cth[8];
#pragma unroll
  for (int i = 0; i < 8; i++) cth[i] = __cosf(fth[i]);

  float pool = 0.f;
  int tok0 = blockIdx.x * 16 + w * 4;
  for (int it = 0; it < 4; ++it) {
    int tok = tok0 + it;
    size_t base = (size_t)tok * Dd + lane;
    float xd = x[base];
    float ov = o_out[base];                              // coalesced
    float psv = ps_out[(size_t)tok * 8 + (lane >> 3)];   // 8-lane broadcast
    float av = ov * (1.0f / psv);
    float y0 = 0.f, y1 = 0.f, y2 = 0.f, y3 = 0.f;
#pragma unroll
    for (int k = 0; k < 64; k += 4) {
      y0 = fmaf(rdlane(av, k),     wc[k],     y0);
      y1 = fmaf(rdlane(av, k + 1), wc[k + 1], y1);
      y2 = fmaf(rdlane(av, k + 2), wc[k + 2], y2);
      y3 = fmaf(rdlane(av, k + 3), wc[k + 3], y3);
    }
    float r = xd + ((y0 + y1) + (y2 + y3));
    float mu = wave_reduce_sum(r) * (1.f / 64.f);
    float tt = r - mu;
    float var = wave_reduce_sum(tt * tt) * (1.f / 64.f);
    float x1 = tt * rsqrtf(var + 1e-5f) * g1d + b1d;
    // quantum FFN
    float z[8];
#pragma unroll
    for (int i = 0; i < 8; i++) z[i] = __cosf(rdlane(x1, i)) * cth[i];
    float ha = fb1a, hb = fb1b;
#pragma unroll
    for (int i = 0; i < 8; i++) { ha = fmaf(z[i], w1a[i], ha); hb = fmaf(z[i], w1b[i], hb); }
    ha = fmaxf(ha, 0.f); hb = fmaxf(hb, 0.f);
    float f0 = 0.f, f1 = 0.f, f2 = 0.f, f3 = 0.f;
#pragma unroll
    for (int j = 0; j < 64; j += 4) {
      f0 = fmaf(rdlane(ha, j),     w2[j],     f0);
      f1 = fmaf(rdlane(ha, j + 1), w2[j + 1], f1);
      f2 = fmaf(rdlane(ha, j + 2), w2[j + 2], f2);
      f3 = fmaf(rdlane(ha, j + 3), w2[j + 3], f3);
    }
#pragma unroll
    for (int j = 0; j < 64; j += 4) {
      f0 = fmaf(rdlane(hb, j),     w2[64 + j],     f0);
      f1 = fmaf(rdlane(hb, j + 1), w2[64 + j + 1], f1);
      f2 = fmaf(rdlane(hb, j + 2), w2[64 + j + 2], f2);
      f3 = fmaf(rdlane(hb, j + 3), w2[64 + j + 3], f3);
    }
    float f = fb2d + ((f0 + f1) + (f2 + f3));
    float r2 = x1 + f;
    float mu2 = wave_reduce_sum(r2) * (1.f / 64.f);
    float t2 = r2 - mu2;
    float var2 = wave_reduce_sum(t2 * t2) * (1.f / 64.f);
    float xo = t2 * rsqrtf(var2 + 1e-5f) * g2d + b2d;
    x[base] = xo;
    pool += xo;
  }
  if (do_partial) {
    red[w][lane] = pool;
    __syncthreads();
    if (w == 0) {
      float s = red[0][lane] + red[1][lane] + red[2][lane] + red[3][lane];
      partial[(size_t)blockIdx.x * 64 + lane] = s;
    }
  }
}

// ------------------------------------------------ pooled mean + MLP head
__global__ __launch_bounds__(128) void head_kernel(
    const float* __restrict__ partial,   // [1024][64]
    const float* eW1, const float* eb1, const float* eW2, const float* eb2,
    const float* eW3, const float* eb3, const float* dW1, const float* db1v,
    const float* dW2, const float* db2v, const float* dW3, const float* db3v,
    const float* cW, const float* cb, float* __restrict__ out) {
  __shared__ float bufP[64];
  __shared__ float bufA[128];
  __shared__ float bufB[128];
  int b = blockIdx.x, t = threadIdx.x;
  if (t < 64) {
    float s = 0.f;
    for (int c = 0; c < 64; ++c) s += partial[(size_t)(b * 64 + c) * 64 + t];
    bufP[t] = s * (1.f / 1024.f);
  }
  __syncthreads();
  {
    float v = eb1[t];
    for (int d = 0; d < 64; d++) v = fmaf(bufP[d], eW1[t * 64 + d], v);
    bufA[t] = fmaxf(v, 0.f);
  }
  __syncthreads();
  if (t < 64) {
    float v = eb2[t];
    for (int j = 0; j < 128; j++) v = fmaf(bufA[j], eW2[t * 128 + j], v);
    bufB[t] = fmaxf(v, 0.f);
  }
  __syncthreads();
  if (t < 32) {
    float v = eb3[t];
    for (int d = 0; d < 64; d++) v = fmaf(bufB[d], eW3[t * 64 + d], v);
    bufA[t] = v;   // latent in bufA[0..31]
  }
  __syncthreads();
  if (t < 64) {
    float v = db1v[t];
    for (int k = 0; k < 32; k++) v = fmaf(bufA[k], dW1[t * 32 + k], v);
    bufB[t] = fmaxf(v, 0.f);
  }
  __syncthreads();
  {
    float v = db2v[t];
    for (int k = 0; k < 64; k++) v = fmaf(bufB[k], dW2[t * 64 + k], v);
    bufA[t] = fmaxf(v, 0.f);
  }
  __syncthreads();
  if (t < 64) {
    float v = db3v[t];
    for (int j = 0; j < 128; j++) v = fmaf(bufA[j], dW3[t * 128 + j], v);
    bufB[t] = v;
  }
  __syncthreads();
  if (t < 10) {
    float v = cb[t];
    for (int d = 0; d < 64; d++) v = fmaf(bufB[d], cW[t * 64 + d], v);
    out[b * 10 + t] = v;
  }
}

extern "C" void kernel_launch(void* const* d_in, const int* in_sizes, int n_in,
                              void* d_out, int out_size, void* d_ws, size_t ws_size,
                              hipStream_t stream) {
  const int*   tokens     = (const int*)d_in[0];
  const float* emb        = (const float*)d_in[1];
  const float* attn_theta = (const float*)d_in[2];
  const float* combine_W  = (const float*)d_in[3];
  const float* ln1_g      = (const float*)d_in[4];
  const float* ln1_b      = (const float*)d_in[5];
  const float* ln2_g      = (const float*)d_in[6];
  const float* ln2_b      = (const float*)d_in[7];
  const float* ffn_theta  = (const float*)d_in[8];
  const float* ffn_W1     = (const float*)d_in[9];
  const float* ffn_b1     = (const float*)d_in[10];
  const float* ffn_W2     = (const float*)d_in[11];
  const float* ffn_b2     = (const float*)d_in[12];
  const float* enc_W1 = (const float*)d_in[13]; const float* enc_b1 = (const float*)d_in[14];
  const float* enc_W2 = (const float*)d_in[15]; const float* enc_b2 = (const float*)d_in[16];
  const float* enc_W3 = (const float*)d_in[17]; const float* enc_b3 = (const float*)d_in[18];
  const float* dec_W1 = (const float*)d_in[19]; const float* dec_b1 = (const float*)d_in[20];
  const float* dec_W2 = (const float*)d_in[21]; const float* dec_b2 = (const float*)d_in[22];
  const float* dec_W3 = (const float*)d_in[23]; const float* dec_b3 = (const float*)d_in[24];
  const float* cls_W  = (const float*)d_in[25]; const float* cls_b  = (const float*)d_in[26];

  float* x       = (float*)d_ws;                      // 1M floats
  float* o_out   = x + (size_t)TOKENS * 64;           // 1M floats
  float* ps_out  = o_out + (size_t)TOKENS * 64;       // 128K floats
  float* partial = ps_out + (size_t)TOKENS * 8;       // 64K floats
  float* out     = (float*)d_out;

  embed_kernel<<<(TOKENS * 32 + 255) / 256, 256, 0, stream>>>(tokens, emb, x);
  for (int l = 0; l < 2; ++l) {
    attn_kernel<<<128 * 8, 256, 0, stream>>>(x, attn_theta + l * 8, o_out, ps_out);
    tail_kernel<<<TOKENS / 16, 256, 0, stream>>>(
        x, o_out, ps_out, combine_W + l * 4096,
        ln1_g + l * 64, ln1_b + l * 64, ln2_g + l * 64, ln2_b + l * 64,
        ffn_theta + l * 8, ffn_W1 + l * 1024, ffn_b1 + l * 128,
        ffn_W2 + l * 8192, ffn_b2 + l * 64, partial, (l == 1) ? 1 : 0);
  }
  head_kernel<<<16, 128, 0, stream>>>(partial, enc_W1, enc_b1, enc_W2, enc_b2,
                                      enc_W3, enc_b3, dec_W1, dec_b1, dec_W2,
                                      dec_b2, dec_W3, dec_b3, cls_W, cls_b, out);
}

// Round 9
// 139.572 us; speedup vs baseline: 1.1140x; 1.1140x over previous
//
#include <hip/hip_runtime.h>
#include <math.h>

typedef _Float16 h2 __attribute__((ext_vector_type(2)));
typedef __fp16 hh4 __attribute__((ext_vector_type(4)));
typedef float f4 __attribute__((ext_vector_type(4)));

#define Bsz 16
#define Ssz 1024
#define TOKENS (Bsz * Ssz)   // 16384
#define Dd 64
#define Hh 8

#if __has_builtin(__builtin_amdgcn_exp2f)
  #define EXPFN(x) __builtin_amdgcn_exp2f(x)
  #define SQRT_PRESCALE 0.7141921f     // sqrt((1/sqrt(8)) * log2(e))
#else
  #define EXPFN(x) __expf(x)
  #define SQRT_PRESCALE 0.5946036f     // sqrt(1/sqrt(8))
#endif

#if __has_builtin(__builtin_amdgcn_mfma_f32_16x16x16_f16)
  #define MFMA16(a, b, c) __builtin_amdgcn_mfma_f32_16x16x16_f16(a, b, c, 0, 0, 0)
#else
  #define MFMA16(a, b, c) __builtin_amdgcn_mfma_f32_16x16x16f16(a, b, c, 0, 0, 0)
#endif

__device__ __forceinline__ h2 pkrtz(float a, float b) {
#if __has_builtin(__builtin_amdgcn_cvt_pkrtz)
  return __builtin_bit_cast(h2, __builtin_amdgcn_cvt_pkrtz(a, b));
#else
  h2 r; r.x = (_Float16)a; r.y = (_Float16)b; return r;
#endif
}
__device__ __forceinline__ unsigned int as_u32(h2 v) {
  return __builtin_bit_cast(unsigned int, v);
}
__device__ __forceinline__ hh4 bc4(uint2 u) {
  return __builtin_bit_cast(hh4, u);
}

#if __has_builtin(__builtin_amdgcn_readlane)
__device__ __forceinline__ float rdlane(float v, int l) {
  return __int_as_float(__builtin_amdgcn_readlane(__float_as_int(v), l));
}
#else
__device__ __forceinline__ float rdlane(float v, int l) { return __shfl(v, l, 64); }
#endif

__device__ __forceinline__ float wave_reduce_sum(float v) {
#pragma unroll
  for (int off = 32; off >= 1; off >>= 1) v += __shfl_xor(v, off, 64);
  return v;
}

// quantum head q-vector for one token/head
__device__ __forceinline__ void qheads(const float* __restrict__ xp,
                                       const float* th, float* o) {
  float4 v0 = *(const float4*)(xp);
  float4 v1 = *(const float4*)(xp + 4);
  float c0 = __cosf(v0.x + th[0]), c1 = __cosf(v0.y + th[1]);
  float c2 = __cosf(v0.z + th[2]), c3 = __cosf(v0.w + th[3]);
  float c4 = __cosf(v1.x + th[4]), c5 = __cosf(v1.y + th[5]);
  float c6 = __cosf(v1.z + th[6]), c7 = __cosf(v1.w + th[7]);
  float cp = c0;
  cp *= c1; o[1] = cp; cp *= c2; o[2] = cp; cp *= c3; o[3] = cp;
  cp *= c4; o[4] = cp; cp *= c5; o[5] = cp; cp *= c6; o[6] = cp;
  cp *= c7; o[7] = cp;
  o[0] = c1 * c2 * c3 * c4 * c5 * c6 * c7;
}

// ---------------------------------------------------------------- embed + pos
__global__ __launch_bounds__(256) void embed_kernel(
    const int* __restrict__ tokens, const float* __restrict__ emb,
    float* __restrict__ x) {
  int gid = blockIdx.x * 256 + threadIdx.x;   // 0 .. TOKENS*32-1
  if (gid >= TOKENS * 32) return;
  int d2 = gid & 31;
  int ts = gid >> 5;
  int s  = ts & (Ssz - 1);
  int tok = tokens[ts];
  float freq = __expf((float)(2 * d2) * (-0.14391156831f));
  float ang = (float)s * freq;
  float sn, cs;
  __sincosf(ang, &sn, &cs);
  float2 e2 = *(const float2*)&emb[(size_t)tok * Dd + 2 * d2];
  float2 r;
  r.x = e2.x + sn;
  r.y = e2.y + cs;
  *(float2*)&x[(size_t)ts * Dd + 2 * d2] = r;
}

// ------------------------------------------------- MFMA flash attention
// grid = 128 bh * 8 rowsplits = 1024 blocks, 256 threads (4 waves).
// LDS 32.1 KB -> 4 blocks/CU. S^T tile = mfma(A=keys, B=rows); exp2;
// O^T tile += mfma(A=Q^T (8 real d-rows), B=P^T). D-rows 8-15 are garbage
// and discarded by the g<2 store guard. Even/odd split accumulators break
// the 64-deep dependent MFMA chain.
__global__ __launch_bounds__(256, 4) void attn_kernel(
    const float* __restrict__ x, const float* __restrict__ theta,
    float* __restrict__ o_out, float* __restrict__ ps_out) {
  __shared__ unsigned int qrs[Ssz * 4 + 2];  // [k][4]: f16x2 pairs, x sqrt(scale); +2 zero pad
  __shared__ unsigned int qtt[8 * 514];      // [d<8][514]: (k,k+1) f16 pairs, unscaled
  int blk = blockIdx.x;
  int bh = blk >> 3, split = blk & 7;
  int b = bh >> 3, h = bh & 7;
  int t = threadIdx.x;

  float th[8];
#pragma unroll
  for (int i = 0; i < 8; i++) th[i] = theta[i];

  const float* xb = x + (size_t)b * Ssz * Dd + h * 8;

  // stage 4 consecutive rows per thread
#pragma unroll
  for (int i = 0; i < 4; i += 2) {
    int k0 = t * 4 + i;
    float oa[8], ob[8];
    qheads(xb + (size_t)k0 * Dd, th, oa);
    qheads(xb + (size_t)(k0 + 1) * Dd, th, ob);
    uint4 wa, wb;
    wa.x = as_u32(pkrtz(oa[0] * SQRT_PRESCALE, oa[1] * SQRT_PRESCALE));
    wa.y = as_u32(pkrtz(oa[2] * SQRT_PRESCALE, oa[3] * SQRT_PRESCALE));
    wa.z = as_u32(pkrtz(oa[4] * SQRT_PRESCALE, oa[5] * SQRT_PRESCALE));
    wa.w = as_u32(pkrtz(oa[6] * SQRT_PRESCALE, oa[7] * SQRT_PRESCALE));
    wb.x = as_u32(pkrtz(ob[0] * SQRT_PRESCALE, ob[1] * SQRT_PRESCALE));
    wb.y = as_u32(pkrtz(ob[2] * SQRT_PRESCALE, ob[3] * SQRT_PRESCALE));
    wb.z = as_u32(pkrtz(ob[4] * SQRT_PRESCALE, ob[5] * SQRT_PRESCALE));
    wb.w = as_u32(pkrtz(ob[6] * SQRT_PRESCALE, ob[7] * SQRT_PRESCALE));
    *(uint4*)&qrs[k0 * 4] = wa;
    *(uint4*)&qrs[(k0 + 1) * 4] = wb;
#pragma unroll
    for (int d = 0; d < 8; d++)
      qtt[d * 514 + (k0 >> 1)] = as_u32(pkrtz(oa[d], ob[d]));  // unscaled
  }
  if (t == 0) { qrs[Ssz * 4] = 0; qrs[Ssz * 4 + 1] = 0; }
  __syncthreads();

  int l = t & 63, w = t >> 6;
  int g = l >> 4, rr = l & 15;
  int rt0 = split * 8 + w * 2;          // this wave's two row-tiles
  int rowA = rt0 * 16 + rr;
  int rowB = rowA + 16;
  uint2 z2; z2.x = 0; z2.y = 0;
  uint2 buA = (g < 2) ? *(const uint2*)&qrs[rowA * 4 + 2 * g] : z2;
  uint2 buB = (g < 2) ? *(const uint2*)&qrs[rowB * 4 + 2 * g] : z2;
  hh4 BrA = bc4(buA), BrB = bc4(buB);
  // A-operand (keys) read: base/stride so lanes g>=2 hit the zero pad
  int aoff  = (g < 2) ? (rr * 4 + 2 * g) : (Ssz * 4);
  int astep = (g < 2) ? 64 : 0;
  int qoff  = (rr & 7) * 514 + 2 * g;   // Q^T read (d-row rr&7)
  f4 zf = {0.f, 0.f, 0.f, 0.f};
  f4 accA0 = zf, accB0 = zf, accA1 = zf, accB1 = zf;
  float psA0 = 0.f, psB0 = 0.f, psA1 = 0.f, psB1 = 0.f;

#pragma unroll 4
  for (int kt = 0; kt < 64; kt += 2) {
    // even kt
    {
      uint2 au = *(const uint2*)&qrs[aoff + kt * astep];
      hh4 Ak = bc4(au);
      f4 sA = MFMA16(Ak, BrA, zf);
      f4 sB = MFMA16(Ak, BrB, zf);
      float pA0 = EXPFN(sA.x), pA1 = EXPFN(sA.y), pA2 = EXPFN(sA.z), pA3 = EXPFN(sA.w);
      float pB0 = EXPFN(sB.x), pB1 = EXPFN(sB.y), pB2 = EXPFN(sB.z), pB3 = EXPFN(sB.w);
      psA0 += (pA0 + pA1) + (pA2 + pA3);
      psB0 += (pB0 + pB1) + (pB2 + pB3);
      uint2 pbA, pbB;
      pbA.x = as_u32(pkrtz(pA0, pA1)); pbA.y = as_u32(pkrtz(pA2, pA3));
      pbB.x = as_u32(pkrtz(pB0, pB1)); pbB.y = as_u32(pkrtz(pB2, pB3));
      uint2 qt = *(const uint2*)&qtt[qoff + kt * 8];
      hh4 Aq = bc4(qt);
      accA0 = MFMA16(Aq, bc4(pbA), accA0);
      accB0 = MFMA16(Aq, bc4(pbB), accB0);
    }
    // odd kt
    {
      uint2 au = *(const uint2*)&qrs[aoff + (kt + 1) * astep];
      hh4 Ak = bc4(au);
      f4 sA = MFMA16(Ak, BrA, zf);
      f4 sB = MFMA16(Ak, BrB, zf);
      float pA0 = EXPFN(sA.x), pA1 = EXPFN(sA.y), pA2 = EXPFN(sA.z), pA3 = EXPFN(sA.w);
      float pB0 = EXPFN(sB.x), pB1 = EXPFN(sB.y), pB2 = EXPFN(sB.z), pB3 = EXPFN(sB.w);
      psA1 += (pA0 + pA1) + (pA2 + pA3);
      psB1 += (pB0 + pB1) + (pB2 + pB3);
      uint2 pbA, pbB;
      pbA.x = as_u32(pkrtz(pA0, pA1)); pbA.y = as_u32(pkrtz(pA2, pA3));
      pbB.x = as_u32(pkrtz(pB0, pB1)); pbB.y = as_u32(pkrtz(pB2, pB3));
      uint2 qt = *(const uint2*)&qtt[qoff + (kt + 1) * 8];
      hh4 Aq = bc4(qt);
      accA1 = MFMA16(Aq, bc4(pbA), accA1);
      accB1 = MFMA16(Aq, bc4(pbB), accB1);
    }
  }
  f4 accA = accA0 + accA1;
  f4 accB = accB0 + accB1;
  float psA = psA0 + psA1, psB = psB0 + psB1;
  psA += __shfl_xor(psA, 16, 64); psA += __shfl_xor(psA, 32, 64);
  psB += __shfl_xor(psB, 16, 64); psB += __shfl_xor(psB, 32, 64);

  size_t tokA = (size_t)b * Ssz + rowA;
  size_t tokB = (size_t)b * Ssz + rowB;
  if (g < 2) {   // lanes 0..31 hold valid d = 4g+reg
    *(f4*)&o_out[tokA * 64 + h * 8 + 4 * g] = accA;
    *(f4*)&o_out[tokB * 64 + h * 8 + 4 * g] = accB;
  }
  if (l < 16) {
    ps_out[tokA * 8 + h] = psA;
    ps_out[tokB * 8 + h] = psB;
  }
}

// ---- tail1: normalize + combine-matvec + residual + LN1 (in-place on x)
__global__ __launch_bounds__(256) void tail1_kernel(
    float* __restrict__ x, const float* __restrict__ o_out,
    const float* __restrict__ ps_out, const float* __restrict__ Wc,
    const float* __restrict__ g1, const float* __restrict__ bb1) {
  int lane = threadIdx.x & 63, w = threadIdx.x >> 6;
  float wc[64];
#pragma unroll
  for (int i = 0; i < 16; i++) {
    float4 v = *(const float4*)&Wc[lane * 64 + i * 4];
    wc[4 * i] = v.x; wc[4 * i + 1] = v.y; wc[4 * i + 2] = v.z; wc[4 * i + 3] = v.w;
  }
  float g = g1[lane], bb = bb1[lane];
  int tok0 = blockIdx.x * 16 + w * 4;
  for (int it = 0; it < 4; ++it) {
    int tok = tok0 + it;
    size_t base = (size_t)tok * Dd + lane;
    float xd = x[base];
    float ov = o_out[base];                              // coalesced
    float psv = ps_out[(size_t)tok * 8 + (lane >> 3)];   // 8-lane broadcast
    float av = ov * (1.0f / psv);
    float y0 = 0.f, y1 = 0.f, y2 = 0.f, y3 = 0.f;
#pragma unroll
    for (int k = 0; k < 64; k += 4) {
      y0 = fmaf(rdlane(av, k),     wc[k],     y0);
      y1 = fmaf(rdlane(av, k + 1), wc[k + 1], y1);
      y2 = fmaf(rdlane(av, k + 2), wc[k + 2], y2);
      y3 = fmaf(rdlane(av, k + 3), wc[k + 3], y3);
    }
    float r = xd + ((y0 + y1) + (y2 + y3));
    float mu = wave_reduce_sum(r) * (1.f / 64.f);
    float tt = r - mu;
    float var = wave_reduce_sum(tt * tt) * (1.f / 64.f);
    x[base] = tt * rsqrtf(var + 1e-5f) * g + bb;
  }
}

// ------------------- tail2: quantum FFN + residual + LN2 (in-place), pooling
__global__ __launch_bounds__(256) void tail2_kernel(
    float* __restrict__ x,
    const float* __restrict__ g2, const float* __restrict__ bb2,
    const float* __restrict__ fth,
    const float* __restrict__ W1, const float* __restrict__ fb1,
    const float* __restrict__ W2, const float* __restrict__ fb2,
    float* __restrict__ partial, int do_partial) {
  __shared__ float red[4][64];
  int lane = threadIdx.x & 63, w = threadIdx.x >> 6;
  float w2[128];
#pragma unroll
  for (int i = 0; i < 32; i++) {
    float4 v = *(const float4*)&W2[lane * 128 + i * 4];
    w2[4 * i] = v.x; w2[4 * i + 1] = v.y; w2[4 * i + 2] = v.z; w2[4 * i + 3] = v.w;
  }
  float w1a[8], w1b[8];
#pragma unroll
  for (int i = 0; i < 8; i++) {
    w1a[i] = W1[lane * 8 + i];
    w1b[i] = W1[(lane + 64) * 8 + i];
  }
  float fb1a = fb1[lane], fb1b = fb1[lane + 64];
  float g = g2[lane], bb = bb2[lane];
  float fb2d = fb2[lane];
  float cth[8];
#pragma unroll
  for (int i = 0; i < 8; i++) cth[i] = __cosf(fth[i]);

  float pool = 0.f;
  int tok0 = blockIdx.x * 16 + w * 4;
  for (int it = 0; it < 4; ++it) {
    size_t base = (size_t)(tok0 + it) * Dd + lane;
    float x1 = x[base];
    float z[8];
#pragma unroll
    for (int i = 0; i < 8; i++) z[i] = __cosf(rdlane(x1, i)) * cth[i];
    float ha = fb1a, hb = fb1b;
#pragma unroll
    for (int i = 0; i < 8; i++) { ha = fmaf(z[i], w1a[i], ha); hb = fmaf(z[i], w1b[i], hb); }
    ha = fmaxf(ha, 0.f); hb = fmaxf(hb, 0.f);
    float f0 = 0.f, f1 = 0.f, f2 = 0.f, f3 = 0.f;
#pragma unroll
    for (int j = 0; j < 64; j += 4) {
      f0 = fmaf(rdlane(ha, j),     w2[j],     f0);
      f1 = fmaf(rdlane(ha, j + 1), w2[j + 1], f1);
      f2 = fmaf(rdlane(ha, j + 2), w2[j + 2], f2);
      f3 = fmaf(rdlane(ha, j + 3), w2[j + 3], f3);
    }
#pragma unroll
    for (int j = 0; j < 64; j += 4) {
      f0 = fmaf(rdlane(hb, j),     w2[64 + j],     f0);
      f1 = fmaf(rdlane(hb, j + 1), w2[64 + j + 1], f1);
      f2 = fmaf(rdlane(hb, j + 2), w2[64 + j + 2], f2);
      f3 = fmaf(rdlane(hb, j + 3), w2[64 + j + 3], f3);
    }
    float f = fb2d + ((f0 + f1) + (f2 + f3));
    float r2 = x1 + f;
    float mu2 = wave_reduce_sum(r2) * (1.f / 64.f);
    float t2 = r2 - mu2;
    float var2 = wave_reduce_sum(t2 * t2) * (1.f / 64.f);
    float xo = t2 * rsqrtf(var2 + 1e-5f) * g + bb;
    x[base] = xo;
    pool += xo;
  }
  if (do_partial) {
    red[w][lane] = pool;
    __syncthreads();
    if (w == 0) {
      float s = red[0][lane] + red[1][lane] + red[2][lane] + red[3][lane];
      partial[(size_t)blockIdx.x * 64 + lane] = s;
    }
  }
}

// ------------------------------------------------ pooled mean + MLP head
__global__ __launch_bounds__(128) void head_kernel(
    const float* __restrict__ partial,   // [1024][64]
    const float* eW1, const float* eb1, const float* eW2, const float* eb2,
    const float* eW3, const float* eb3, const float* dW1, const float* db1v,
    const float* dW2, const float* db2v, const float* dW3, const float* db3v,
    const float* cW, const float* cb, float* __restrict__ out) {
  __shared__ float bufP[64];
  __shared__ float bufA[128];
  __shared__ float bufB[128];
  int b = blockIdx.x, t = threadIdx.x;
  if (t < 64) {
    float s = 0.f;
    for (int c = 0; c < 64; ++c) s += partial[(size_t)(b * 64 + c) * 64 + t];
    bufP[t] = s * (1.f / 1024.f);
  }
  __syncthreads();
  {
    float v = eb1[t];
    for (int d = 0; d < 64; d++) v = fmaf(bufP[d], eW1[t * 64 + d], v);
    bufA[t] = fmaxf(v, 0.f);
  }
  __syncthreads();
  if (t < 64) {
    float v = eb2[t];
    for (int j = 0; j < 128; j++) v = fmaf(bufA[j], eW2[t * 128 + j], v);
    bufB[t] = fmaxf(v, 0.f);
  }
  __syncthreads();
  if (t < 32) {
    float v = eb3[t];
    for (int d = 0; d < 64; d++) v = fmaf(bufB[d], eW3[t * 64 + d], v);
    bufA[t] = v;   // latent in bufA[0..31]
  }
  __syncthreads();
  if (t < 64) {
    float v = db1v[t];
    for (int k = 0; k < 32; k++) v = fmaf(bufA[k], dW1[t * 32 + k], v);
    bufB[t] = fmaxf(v, 0.f);
  }
  __syncthreads();
  {
    float v = db2v[t];
    for (int k = 0; k < 64; k++) v = fmaf(bufB[k], dW2[t * 64 + k], v);
    bufA[t] = fmaxf(v, 0.f);
  }
  __syncthreads();
  if (t < 64) {
    float v = db3v[t];
    for (int j = 0; j < 128; j++) v = fmaf(bufA[j], dW3[t * 128 + j], v);
    bufB[t] = v;
  }
  __syncthreads();
  if (t < 10) {
    float v = cb[t];
    for (int d = 0; d < 64; d++) v = fmaf(bufB[d], cW[t * 64 + d], v);
    out[b * 10 + t] = v;
  }
}

extern "C" void kernel_launch(void* const* d_in, const int* in_sizes, int n_in,
                              void* d_out, int out_size, void* d_ws, size_t ws_size,
                              hipStream_t stream) {
  const int*   tokens     = (const int*)d_in[0];
  const float* emb        = (const float*)d_in[1];
  const float* attn_theta = (const float*)d_in[2];
  const float* combine_W  = (const float*)d_in[3];
  const float* ln1_g      = (const float*)d_in[4];
  const float* ln1_b      = (const float*)d_in[5];
  const float* ln2_g      = (const float*)d_in[6];
  const float* ln2_b      = (const float*)d_in[7];
  const float* ffn_theta  = (const float*)d_in[8];
  const float* ffn_W1     = (const float*)d_in[9];
  const float* ffn_b1     = (const float*)d_in[10];
  const float* ffn_W2     = (const float*)d_in[11];
  const float* ffn_b2     = (const float*)d_in[12];
  const float* enc_W1 = (const float*)d_in[13]; const float* enc_b1 = (const float*)d_in[14];
  const float* enc_W2 = (const float*)d_in[15]; const float* enc_b2 = (const float*)d_in[16];
  const float* enc_W3 = (const float*)d_in[17]; const float* enc_b3 = (const float*)d_in[18];
  const float* dec_W1 = (const float*)d_in[19]; const float* dec_b1 = (const float*)d_in[20];
  const float* dec_W2 = (const float*)d_in[21]; const float* dec_b2 = (const float*)d_in[22];
  const float* dec_W3 = (const float*)d_in[23]; const float* dec_b3 = (const float*)d_in[24];
  const float* cls_W  = (const float*)d_in[25]; const float* cls_b  = (const float*)d_in[26];

  float* x       = (float*)d_ws;                      // 1M floats
  float* o_out   = x + (size_t)TOKENS * 64;           // 1M floats
  float* ps_out  = o_out + (size_t)TOKENS * 64;       // 128K floats
  float* partial = ps_out + (size_t)TOKENS * 8;       // 64K floats
  float* out     = (float*)d_out;

  embed_kernel<<<(TOKENS * 32 + 255) / 256, 256, 0, stream>>>(tokens, emb, x);
  for (int l = 0; l < 2; ++l) {
    attn_kernel<<<128 * 8, 256, 0, stream>>>(x, attn_theta + l * 8, o_out, ps_out);
    tail1_kernel<<<TOKENS / 16, 256, 0, stream>>>(
        x, o_out, ps_out, combine_W + l * 4096, ln1_g + l * 64, ln1_b + l * 64);
    tail2_kernel<<<TOKENS / 16, 256, 0, stream>>>(
        x, ln2_g + l * 64, ln2_b + l * 64,
        ffn_theta + l * 8, ffn_W1 + l * 1024, ffn_b1 + l * 128,
        ffn_W2 + l * 8192, ffn_b2 + l * 64, partial, (l == 1) ? 1 : 0);
  }
  head_kernel<<<16, 128, 0, stream>>>(partial, enc_W1, enc_b1, enc_W2, enc_b2,
                                      enc_W3, enc_b3, dec_W1, dec_b1, dec_W2,
                                      dec_b2, dec_W3, dec_b3, cls_W, cls_b, out);
}

// Round 10
// 118.690 us; speedup vs baseline: 1.3101x; 1.1759x over previous
//
#include <hip/hip_runtime.h>
#include <math.h>

typedef _Float16 h2 __attribute__((ext_vector_type(2)));
typedef __fp16 hh4 __attribute__((ext_vector_type(4)));
typedef float f4 __attribute__((ext_vector_type(4)));

#define Bsz 16
#define Ssz 1024
#define TOKENS (Bsz * Ssz)   // 16384
#define Dd 64
#define Hh 8
#define QTTS 520             // qtt LDS row stride (words): 520%32=8 -> 2-way banks

#if __has_builtin(__builtin_amdgcn_exp2f)
  #define EXPFN(x) __builtin_amdgcn_exp2f(x)
  #define SQRT_PRESCALE 0.7141921f     // sqrt((1/sqrt(8)) * log2(e))
#else
  #define EXPFN(x) __expf(x)
  #define SQRT_PRESCALE 0.5946036f     // sqrt(1/sqrt(8))
#endif

#if __has_builtin(__builtin_amdgcn_mfma_f32_16x16x16_f16)
  #define MFMA16(a, b, c) __builtin_amdgcn_mfma_f32_16x16x16_f16(a, b, c, 0, 0, 0)
#else
  #define MFMA16(a, b, c) __builtin_amdgcn_mfma_f32_16x16x16f16(a, b, c, 0, 0, 0)
#endif

__device__ __forceinline__ h2 pkrtz(float a, float b) {
#if __has_builtin(__builtin_amdgcn_cvt_pkrtz)
  return __builtin_bit_cast(h2, __builtin_amdgcn_cvt_pkrtz(a, b));
#else
  h2 r; r.x = (_Float16)a; r.y = (_Float16)b; return r;
#endif
}
__device__ __forceinline__ unsigned int as_u32(h2 v) {
  return __builtin_bit_cast(unsigned int, v);
}
__device__ __forceinline__ hh4 bc4(uint2 u) {
  return __builtin_bit_cast(hh4, u);
}

#if __has_builtin(__builtin_amdgcn_readlane)
__device__ __forceinline__ float rdlane(float v, int l) {
  return __int_as_float(__builtin_amdgcn_readlane(__float_as_int(v), l));
}
#else
__device__ __forceinline__ float rdlane(float v, int l) { return __shfl(v, l, 64); }
#endif

__device__ __forceinline__ float wave_reduce_sum(float v) {
#pragma unroll
  for (int off = 32; off >= 1; off >>= 1) v += __shfl_xor(v, off, 64);
  return v;
}

// quantum head q-vector for one token/head
__device__ __forceinline__ void qheads(const float* __restrict__ xp,
                                       const float* th, float* o) {
  float4 v0 = *(const float4*)(xp);
  float4 v1 = *(const float4*)(xp + 4);
  float c0 = __cosf(v0.x + th[0]), c1 = __cosf(v0.y + th[1]);
  float c2 = __cosf(v0.z + th[2]), c3 = __cosf(v0.w + th[3]);
  float c4 = __cosf(v1.x + th[4]), c5 = __cosf(v1.y + th[5]);
  float c6 = __cosf(v1.z + th[6]), c7 = __cosf(v1.w + th[7]);
  float cp = c0;
  cp *= c1; o[1] = cp; cp *= c2; o[2] = cp; cp *= c3; o[3] = cp;
  cp *= c4; o[4] = cp; cp *= c5; o[5] = cp; cp *= c6; o[6] = cp;
  cp *= c7; o[7] = cp;
  o[0] = c1 * c2 * c3 * c4 * c5 * c6 * c7;
}

// ---------------------------------------------------------------- embed + pos
__global__ __launch_bounds__(256) void embed_kernel(
    const int* __restrict__ tokens, const float* __restrict__ emb,
    float* __restrict__ x) {
  int gid = blockIdx.x * 256 + threadIdx.x;   // 0 .. TOKENS*32-1
  if (gid >= TOKENS * 32) return;
  int d2 = gid & 31;
  int ts = gid >> 5;
  int s  = ts & (Ssz - 1);
  int tok = tokens[ts];
  float freq = __expf((float)(2 * d2) * (-0.14391156831f));
  float ang = (float)s * freq;
  float sn, cs;
  __sincosf(ang, &sn, &cs);
  float2 e2 = *(const float2*)&emb[(size_t)tok * Dd + 2 * d2];
  float2 r;
  r.x = e2.x + sn;
  r.y = e2.y + cs;
  *(float2*)&x[(size_t)ts * Dd + 2 * d2] = r;
}

// ------------------------------------------------- MFMA flash attention
// grid = 128 bh * 8 rowsplits = 1024 blocks, 256 threads (4 waves).
// LDS ~32.3 KB -> 4 blocks/CU. S^T tile = mfma(A=keys, B=rows); exp2;
// O^T tile += mfma(A=Q^T (8 real d-rows), B=P^T).
__global__ __launch_bounds__(256, 4) void attn_kernel(
    const float* __restrict__ x, const float* __restrict__ theta,
    float* __restrict__ o_out, float* __restrict__ ps_out) {
  __shared__ unsigned int qrs[Ssz * 4 + 2];  // [k][4]: f16x2 pairs, x sqrt(scale); +2 zero pad
  __shared__ unsigned int qtt[8 * QTTS];     // [d<8][pairs (k,k+1)], stride QTTS
  int blk = blockIdx.x;
  int bh = blk >> 3, split = blk & 7;
  int b = bh >> 3, h = bh & 7;
  int t = threadIdx.x;

  float th[8];
#pragma unroll
  for (int i = 0; i < 8; i++) th[i] = theta[i];

  const float* xb = x + (size_t)b * Ssz * Dd + h * 8;

  // stage 4 consecutive rows per thread
#pragma unroll
  for (int i = 0; i < 4; i += 2) {
    int k0 = t * 4 + i;
    float oa[8], ob[8];
    qheads(xb + (size_t)k0 * Dd, th, oa);
    qheads(xb + (size_t)(k0 + 1) * Dd, th, ob);
    uint4 wa, wb;
    wa.x = as_u32(pkrtz(oa[0] * SQRT_PRESCALE, oa[1] * SQRT_PRESCALE));
    wa.y = as_u32(pkrtz(oa[2] * SQRT_PRESCALE, oa[3] * SQRT_PRESCALE));
    wa.z = as_u32(pkrtz(oa[4] * SQRT_PRESCALE, oa[5] * SQRT_PRESCALE));
    wa.w = as_u32(pkrtz(oa[6] * SQRT_PRESCALE, oa[7] * SQRT_PRESCALE));
    wb.x = as_u32(pkrtz(ob[0] * SQRT_PRESCALE, ob[1] * SQRT_PRESCALE));
    wb.y = as_u32(pkrtz(ob[2] * SQRT_PRESCALE, ob[3] * SQRT_PRESCALE));
    wb.z = as_u32(pkrtz(ob[4] * SQRT_PRESCALE, ob[5] * SQRT_PRESCALE));
    wb.w = as_u32(pkrtz(ob[6] * SQRT_PRESCALE, ob[7] * SQRT_PRESCALE));
    *(uint4*)&qrs[k0 * 4] = wa;
    *(uint4*)&qrs[(k0 + 1) * 4] = wb;
#pragma unroll
    for (int d = 0; d < 8; d++)
      qtt[d * QTTS + (k0 >> 1)] = as_u32(pkrtz(oa[d], ob[d]));  // unscaled
  }
  if (t == 0) { qrs[Ssz * 4] = 0; qrs[Ssz * 4 + 1] = 0; }
  __syncthreads();

  int l = t & 63, w = t >> 6;
  int g = l >> 4, rr = l & 15;
  int rt0 = split * 8 + w * 2;          // this wave's two row-tiles
  int rowA = rt0 * 16 + rr;
  int rowB = rowA + 16;
  uint2 z2; z2.x = 0; z2.y = 0;
  uint2 buA = (g < 2) ? *(const uint2*)&qrs[rowA * 4 + 2 * g] : z2;
  uint2 buB = (g < 2) ? *(const uint2*)&qrs[rowB * 4 + 2 * g] : z2;
  hh4 BrA = bc4(buA), BrB = bc4(buB);
  // A-operand (keys) read: base/stride so lanes g>=2 hit the zero pad
  int aoff  = (g < 2) ? (rr * 4 + 2 * g) : (Ssz * 4);
  int astep = (g < 2) ? 64 : 0;
  int qoff  = (rr & 7) * QTTS + 2 * g;  // Q^T read (d-row rr&7)
  f4 zf = {0.f, 0.f, 0.f, 0.f};
  f4 accA0 = zf, accB0 = zf, accA1 = zf, accB1 = zf;
  float psA0 = 0.f, psB0 = 0.f, psA1 = 0.f, psB1 = 0.f;

#pragma unroll 4
  for (int kt = 0; kt < 64; kt += 2) {
    {
      uint2 au = *(const uint2*)&qrs[aoff + kt * astep];
      hh4 Ak = bc4(au);
      f4 sA = MFMA16(Ak, BrA, zf);
      f4 sB = MFMA16(Ak, BrB, zf);
      float pA0 = EXPFN(sA.x), pA1 = EXPFN(sA.y), pA2 = EXPFN(sA.z), pA3 = EXPFN(sA.w);
      float pB0 = EXPFN(sB.x), pB1 = EXPFN(sB.y), pB2 = EXPFN(sB.z), pB3 = EXPFN(sB.w);
      psA0 += (pA0 + pA1) + (pA2 + pA3);
      psB0 += (pB0 + pB1) + (pB2 + pB3);
      uint2 pbA, pbB;
      pbA.x = as_u32(pkrtz(pA0, pA1)); pbA.y = as_u32(pkrtz(pA2, pA3));
      pbB.x = as_u32(pkrtz(pB0, pB1)); pbB.y = as_u32(pkrtz(pB2, pB3));
      uint2 qt = *(const uint2*)&qtt[qoff + kt * 8];
      hh4 Aq = bc4(qt);
      accA0 = MFMA16(Aq, bc4(pbA), accA0);
      accB0 = MFMA16(Aq, bc4(pbB), accB0);
    }
    {
      uint2 au = *(const uint2*)&qrs[aoff + (kt + 1) * astep];
      hh4 Ak = bc4(au);
      f4 sA = MFMA16(Ak, BrA, zf);
      f4 sB = MFMA16(Ak, BrB, zf);
      float pA0 = EXPFN(sA.x), pA1 = EXPFN(sA.y), pA2 = EXPFN(sA.z), pA3 = EXPFN(sA.w);
      float pB0 = EXPFN(sB.x), pB1 = EXPFN(sB.y), pB2 = EXPFN(sB.z), pB3 = EXPFN(sB.w);
      psA1 += (pA0 + pA1) + (pA2 + pA3);
      psB1 += (pB0 + pB1) + (pB2 + pB3);
      uint2 pbA, pbB;
      pbA.x = as_u32(pkrtz(pA0, pA1)); pbA.y = as_u32(pkrtz(pA2, pA3));
      pbB.x = as_u32(pkrtz(pB0, pB1)); pbB.y = as_u32(pkrtz(pB2, pB3));
      uint2 qt = *(const uint2*)&qtt[qoff + (kt + 1) * 8];
      hh4 Aq = bc4(qt);
      accA1 = MFMA16(Aq, bc4(pbA), accA1);
      accB1 = MFMA16(Aq, bc4(pbB), accB1);
    }
  }
  f4 accA = accA0 + accA1;
  f4 accB = accB0 + accB1;
  float psA = psA0 + psA1, psB = psB0 + psB1;
  psA += __shfl_xor(psA, 16, 64); psA += __shfl_xor(psA, 32, 64);
  psB += __shfl_xor(psB, 16, 64); psB += __shfl_xor(psB, 32, 64);

  size_t tokA = (size_t)b * Ssz + rowA;
  size_t tokB = (size_t)b * Ssz + rowB;
  if (g < 2) {   // lanes 0..31 hold valid d = 4g+reg
    *(f4*)&o_out[tokA * 64 + h * 8 + 4 * g] = accA;
    *(f4*)&o_out[tokB * 64 + h * 8 + 4 * g] = accB;
  }
  if (l < 16) {
    ps_out[tokA * 8 + h] = psA;
    ps_out[tokB * 8 + h] = psB;
  }
}

// ---- tail1 (MFMA): normalize + combine-matvec + residual + LN1, in-place on x
// One wave per 16 tokens. A = acts[16 tok][64 k] (f16), B = Wc^T tiles.
// D layout: lane l holds token tok0+4*(l>>4)+reg, d = dc*16 + (l&15).
__global__ __launch_bounds__(64) void tail1_kernel(
    float* __restrict__ x, const float* __restrict__ o_out,
    const float* __restrict__ ps_out, const float* __restrict__ Wc,
    const float* __restrict__ g1, const float* __restrict__ bb1) {
  int l = threadIdx.x & 63;
  int g = l >> 4, c = l & 15;
  int tok0 = blockIdx.x * 16;

  // B fragments: B[k=kc*16+4g+j][col=c] = Wc^T[k][d=dc*16+c] = Wc[dc*16+c][k]
  hh4 Bf[4][4];   // [kc][dc]
#pragma unroll
  for (int dc = 0; dc < 4; dc++)
#pragma unroll
    for (int kc = 0; kc < 4; kc++) {
      float4 wv = *(const float4*)&Wc[(size_t)(dc * 16 + c) * 64 + kc * 16 + 4 * g];
      uint2 u; u.x = as_u32(pkrtz(wv.x, wv.y)); u.y = as_u32(pkrtz(wv.z, wv.w));
      Bf[kc][dc] = bc4(u);
    }

  // A fragments: av[tok=tok0+c][k=kc*16+4g+j] = o_out/psum
  int tka = tok0 + c;
  hh4 Af[4];
#pragma unroll
  for (int kc = 0; kc < 4; kc++) {
    float4 o4 = *(const float4*)&o_out[(size_t)tka * 64 + kc * 16 + 4 * g];
    float inv = 1.0f / ps_out[(size_t)tka * 8 + kc * 2 + (g >> 1)];
    uint2 u;
    u.x = as_u32(pkrtz(o4.x * inv, o4.y * inv));
    u.y = as_u32(pkrtz(o4.z * inv, o4.w * inv));
    Af[kc] = bc4(u);
  }

  f4 zf = {0.f, 0.f, 0.f, 0.f};
  float yy[4][4];   // [dc][r]
#pragma unroll
  for (int dc = 0; dc < 4; dc++) {
    f4 acc = zf;
#pragma unroll
    for (int kc = 0; kc < 4; kc++) acc = MFMA16(Af[kc], Bf[kc][dc], acc);
    yy[dc][0] = acc.x; yy[dc][1] = acc.y; yy[dc][2] = acc.z; yy[dc][3] = acc.w;
  }

  float g1v[4], b1v[4];
#pragma unroll
  for (int dc = 0; dc < 4; dc++) { g1v[dc] = g1[dc * 16 + c]; b1v[dc] = bb1[dc * 16 + c]; }

#pragma unroll
  for (int r = 0; r < 4; r++) {
    int tok = tok0 + 4 * g + r;
    float rv0 = x[(size_t)tok * 64 + c]      + yy[0][r];
    float rv1 = x[(size_t)tok * 64 + 16 + c] + yy[1][r];
    float rv2 = x[(size_t)tok * 64 + 32 + c] + yy[2][r];
    float rv3 = x[(size_t)tok * 64 + 48 + c] + yy[3][r];
    float s = (rv0 + rv1) + (rv2 + rv3);
    s += __shfl_xor(s, 1, 64); s += __shfl_xor(s, 2, 64);
    s += __shfl_xor(s, 4, 64); s += __shfl_xor(s, 8, 64);
    float mu = s * (1.f / 64.f);
    float t0 = rv0 - mu, t1 = rv1 - mu, t2 = rv2 - mu, t3 = rv3 - mu;
    float q = (t0 * t0 + t1 * t1) + (t2 * t2 + t3 * t3);
    q += __shfl_xor(q, 1, 64); q += __shfl_xor(q, 2, 64);
    q += __shfl_xor(q, 4, 64); q += __shfl_xor(q, 8, 64);
    float inv = rsqrtf(q * (1.f / 64.f) + 1e-5f);
    x[(size_t)tok * 64 + c]      = t0 * inv * g1v[0] + b1v[0];
    x[(size_t)tok * 64 + 16 + c] = t1 * inv * g1v[1] + b1v[1];
    x[(size_t)tok * 64 + 32 + c] = t2 * inv * g1v[2] + b1v[2];
    x[(size_t)tok * 64 + 48 + c] = t3 * inv * g1v[3] + b1v[3];
  }
}

// ------------------- tail2: quantum FFN + residual + LN2 (in-place), pooling
__global__ __launch_bounds__(256) void tail2_kernel(
    float* __restrict__ x,
    const float* __restrict__ g2, const float* __restrict__ bb2,
    const float* __restrict__ fth,
    const float* __restrict__ W1, const float* __restrict__ fb1,
    const float* __restrict__ W2, const float* __restrict__ fb2,
    float* __restrict__ partial, int do_partial) {
  __shared__ float red[4][64];
  int lane = threadIdx.x & 63, w = threadIdx.x >> 6;
  float w2[128];
#pragma unroll
  for (int i = 0; i < 32; i++) {
    float4 v = *(const float4*)&W2[lane * 128 + i * 4];
    w2[4 * i] = v.x; w2[4 * i + 1] = v.y; w2[4 * i + 2] = v.z; w2[4 * i + 3] = v.w;
  }
  float w1a[8], w1b[8];
#pragma unroll
  for (int i = 0; i < 8; i++) {
    w1a[i] = W1[lane * 8 + i];
    w1b[i] = W1[(lane + 64) * 8 + i];
  }
  float fb1a = fb1[lane], fb1b = fb1[lane + 64];
  float g = g2[lane], bb = bb2[lane];
  float fb2d = fb2[lane];
  float cth[8];
#pragma unroll
  for (int i = 0; i < 8; i++) cth[i] = __cosf(fth[i]);

  float pool = 0.f;
  int tok0 = blockIdx.x * 16 + w * 4;
  for (int it = 0; it < 4; ++it) {
    size_t base = (size_t)(tok0 + it) * Dd + lane;
    float x1 = x[base];
    float z[8];
#pragma unroll
    for (int i = 0; i < 8; i++) z[i] = __cosf(rdlane(x1, i)) * cth[i];
    float ha = fb1a, hb = fb1b;
#pragma unroll
    for (int i = 0; i < 8; i++) { ha = fmaf(z[i], w1a[i], ha); hb = fmaf(z[i], w1b[i], hb); }
    ha = fmaxf(ha, 0.f); hb = fmaxf(hb, 0.f);
    float f0 = 0.f, f1 = 0.f, f2 = 0.f, f3 = 0.f;
#pragma unroll
    for (int j = 0; j < 64; j += 4) {
      f0 = fmaf(rdlane(ha, j),     w2[j],     f0);
      f1 = fmaf(rdlane(ha, j + 1), w2[j + 1], f1);
      f2 = fmaf(rdlane(ha, j + 2), w2[j + 2], f2);
      f3 = fmaf(rdlane(ha, j + 3), w2[j + 3], f3);
    }
#pragma unroll
    for (int j = 0; j < 64; j += 4) {
      f0 = fmaf(rdlane(hb, j),     w2[64 + j],     f0);
      f1 = fmaf(rdlane(hb, j + 1), w2[64 + j + 1], f1);
      f2 = fmaf(rdlane(hb, j + 2), w2[64 + j + 2], f2);
      f3 = fmaf(rdlane(hb, j + 3), w2[64 + j + 3], f3);
    }
    float f = fb2d + ((f0 + f1) + (f2 + f3));
    float r2 = x1 + f;
    float mu2 = wave_reduce_sum(r2) * (1.f / 64.f);
    float t2 = r2 - mu2;
    float var2 = wave_reduce_sum(t2 * t2) * (1.f / 64.f);
    float xo = t2 * rsqrtf(var2 + 1e-5f) * g + bb;
    x[base] = xo;
    pool += xo;
  }
  if (do_partial) {
    red[w][lane] = pool;
    __syncthreads();
    if (w == 0) {
      float s = red[0][lane] + red[1][lane] + red[2][lane] + red[3][lane];
      partial[(size_t)blockIdx.x * 64 + lane] = s;
    }
  }
}

// ------------------------------------------------ pooled mean + MLP head
__global__ __launch_bounds__(128) void head_kernel(
    const float* __restrict__ partial,   // [1024][64]
    const float* eW1, const float* eb1, const float* eW2, const float* eb2,
    const float* eW3, const float* eb3, const float* dW1, const float* db1v,
    const float* dW2, const float* db2v, const float* dW3, const float* db3v,
    const float* cW, const float* cb, float* __restrict__ out) {
  __shared__ float bufP[64];
  __shared__ float bufA[128];
  __shared__ float bufB[128];
  int b = blockIdx.x, t = threadIdx.x;
  if (t < 64) {
    float s = 0.f;
    for (int c = 0; c < 64; ++c) s += partial[(size_t)(b * 64 + c) * 64 + t];
    bufP[t] = s * (1.f / 1024.f);
  }
  __syncthreads();
  {
    float v = eb1[t];
    for (int d = 0; d < 64; d++) v = fmaf(bufP[d], eW1[t * 64 + d], v);
    bufA[t] = fmaxf(v, 0.f);
  }
  __syncthreads();
  if (t < 64) {
    float v = eb2[t];
    for (int j = 0; j < 128; j++) v = fmaf(bufA[j], eW2[t * 128 + j], v);
    bufB[t] = fmaxf(v, 0.f);
  }
  __syncthreads();
  if (t < 32) {
    float v = eb3[t];
    for (int d = 0; d < 64; d++) v = fmaf(bufB[d], eW3[t * 64 + d], v);
    bufA[t] = v;   // latent in bufA[0..31]
  }
  __syncthreads();
  if (t < 64) {
    float v = db1v[t];
    for (int k = 0; k < 32; k++) v = fmaf(bufA[k], dW1[t * 32 + k], v);
    bufB[t] = fmaxf(v, 0.f);
  }
  __syncthreads();
  {
    float v = db2v[t];
    for (int k = 0; k < 64; k++) v = fmaf(bufB[k], dW2[t * 64 + k], v);
    bufA[t] = fmaxf(v, 0.f);
  }
  __syncthreads();
  if (t < 64) {
    float v = db3v[t];
    for (int j = 0; j < 128; j++) v = fmaf(bufA[j], dW3[t * 128 + j], v);
    bufB[t] = v;
  }
  __syncthreads();
  if (t < 10) {
    float v = cb[t];
    for (int d = 0; d < 64; d++) v = fmaf(bufB[d], cW[t * 64 + d], v);
    out[b * 10 + t] = v;
  }
}

extern "C" void kernel_launch(void* const* d_in, const int* in_sizes, int n_in,
                              void* d_out, int out_size, void* d_ws, size_t ws_size,
                              hipStream_t stream) {
  const int*   tokens     = (const int*)d_in[0];
  const float* emb        = (const float*)d_in[1];
  const float* attn_theta = (const float*)d_in[2];
  const float* combine_W  = (const float*)d_in[3];
  const float* ln1_g      = (const float*)d_in[4];
  const float* ln1_b      = (const float*)d_in[5];
  const float* ln2_g      = (const float*)d_in[6];
  const float* ln2_b      = (const float*)d_in[7];
  const float* ffn_theta  = (const float*)d_in[8];
  const float* ffn_W1     = (const float*)d_in[9];
  const float* ffn_b1     = (const float*)d_in[10];
  const float* ffn_W2     = (const float*)d_in[11];
  const float* ffn_b2     = (const float*)d_in[12];
  const float* enc_W1 = (const float*)d_in[13]; const float* enc_b1 = (const float*)d_in[14];
  const float* enc_W2 = (const float*)d_in[15]; const float* enc_b2 = (const float*)d_in[16];
  const float* enc_W3 = (const float*)d_in[17]; const float* enc_b3 = (const float*)d_in[18];
  const float* dec_W1 = (const float*)d_in[19]; const float* dec_b1 = (const float*)d_in[20];
  const float* dec_W2 = (const float*)d_in[21]; const float* dec_b2 = (const float*)d_in[22];
  const float* dec_W3 = (const float*)d_in[23]; const float* dec_b3 = (const float*)d_in[24];
  const float* cls_W  = (const float*)d_in[25]; const float* cls_b  = (const float*)d_in[26];

  float* x       = (float*)d_ws;                      // 1M floats
  float* o_out   = x + (size_t)TOKENS * 64;           // 1M floats
  float* ps_out  = o_out + (size_t)TOKENS * 64;       // 128K floats
  float* partial = ps_out + (size_t)TOKENS * 8;       // 64K floats
  float* out     = (float*)d_out;

  embed_kernel<<<(TOKENS * 32 + 255) / 256, 256, 0, stream>>>(tokens, emb, x);
  for (int l = 0; l < 2; ++l) {
    attn_kernel<<<128 * 8, 256, 0, stream>>>(x, attn_theta + l * 8, o_out, ps_out);
    tail1_kernel<<<TOKENS / 16, 64, 0, stream>>>(
        x, o_out, ps_out, combine_W + l * 4096, ln1_g + l * 64, ln1_b + l * 64);
    tail2_kernel<<<TOKENS / 16, 256, 0, stream>>>(
        x, ln2_g + l * 64, ln2_b + l * 64,
        ffn_theta + l * 8, ffn_W1 + l * 1024, ffn_b1 + l * 128,
        ffn_W2 + l * 8192, ffn_b2 + l * 64, partial, (l == 1) ? 1 : 0);
  }
  head_kernel<<<16, 128, 0, stream>>>(partial, enc_W1, enc_b1, enc_W2, enc_b2,
                                      enc_W3, enc_b3, dec_W1, dec_b1, dec_W2,
                                      dec_b2, dec_W3, dec_b3, cls_W, cls_b, out);
}

// Round 11
// 102.254 us; speedup vs baseline: 1.5206x; 1.1607x over previous
//
#include <hip/hip_runtime.h>
#include <math.h>

typedef _Float16 h2 __attribute__((ext_vector_type(2)));
typedef __fp16 hh4 __attribute__((ext_vector_type(4)));
typedef float f4 __attribute__((ext_vector_type(4)));

#define Bsz 16
#define Ssz 1024
#define TOKENS (Bsz * Ssz)   // 16384
#define Dd 64
#define Hh 8
#define QTTS 520             // qtt LDS row stride (words): 520%32=8 -> 2-way banks

#if __has_builtin(__builtin_amdgcn_exp2f)
  #define EXPFN(x) __builtin_amdgcn_exp2f(x)
  #define SQRT_PRESCALE 0.7141921f     // sqrt((1/sqrt(8)) * log2(e))
#else
  #define EXPFN(x) __expf(x)
  #define SQRT_PRESCALE 0.5946036f     // sqrt(1/sqrt(8))
#endif

#if __has_builtin(__builtin_amdgcn_mfma_f32_16x16x16_f16)
  #define MFMA16(a, b, c) __builtin_amdgcn_mfma_f32_16x16x16_f16(a, b, c, 0, 0, 0)
#else
  #define MFMA16(a, b, c) __builtin_amdgcn_mfma_f32_16x16x16f16(a, b, c, 0, 0, 0)
#endif

__device__ __forceinline__ h2 pkrtz(float a, float b) {
#if __has_builtin(__builtin_amdgcn_cvt_pkrtz)
  return __builtin_bit_cast(h2, __builtin_amdgcn_cvt_pkrtz(a, b));
#else
  h2 r; r.x = (_Float16)a; r.y = (_Float16)b; return r;
#endif
}
__device__ __forceinline__ unsigned int as_u32(h2 v) {
  return __builtin_bit_cast(unsigned int, v);
}
__device__ __forceinline__ hh4 bc4(uint2 u) {
  return __builtin_bit_cast(hh4, u);
}

#if __has_builtin(__builtin_amdgcn_readlane)
__device__ __forceinline__ float rdlane(float v, int l) {
  return __int_as_float(__builtin_amdgcn_readlane(__float_as_int(v), l));
}
#else
__device__ __forceinline__ float rdlane(float v, int l) { return __shfl(v, l, 64); }
#endif

// quantum head q-vector for one token/head
__device__ __forceinline__ void qheads(const float* __restrict__ xp,
                                       const float* th, float* o) {
  float4 v0 = *(const float4*)(xp);
  float4 v1 = *(const float4*)(xp + 4);
  float c0 = __cosf(v0.x + th[0]), c1 = __cosf(v0.y + th[1]);
  float c2 = __cosf(v0.z + th[2]), c3 = __cosf(v0.w + th[3]);
  float c4 = __cosf(v1.x + th[4]), c5 = __cosf(v1.y + th[5]);
  float c6 = __cosf(v1.z + th[6]), c7 = __cosf(v1.w + th[7]);
  float cp = c0;
  cp *= c1; o[1] = cp; cp *= c2; o[2] = cp; cp *= c3; o[3] = cp;
  cp *= c4; o[4] = cp; cp *= c5; o[5] = cp; cp *= c6; o[6] = cp;
  cp *= c7; o[7] = cp;
  o[0] = c1 * c2 * c3 * c4 * c5 * c6 * c7;
}

// ---------------------------------------------------------------- embed + pos
__global__ __launch_bounds__(256) void embed_kernel(
    const int* __restrict__ tokens, const float* __restrict__ emb,
    float* __restrict__ x) {
  int gid = blockIdx.x * 256 + threadIdx.x;   // 0 .. TOKENS*32-1
  if (gid >= TOKENS * 32) return;
  int d2 = gid & 31;
  int ts = gid >> 5;
  int s  = ts & (Ssz - 1);
  int tok = tokens[ts];
  float freq = __expf((float)(2 * d2) * (-0.14391156831f));
  float ang = (float)s * freq;
  float sn, cs;
  __sincosf(ang, &sn, &cs);
  float2 e2 = *(const float2*)&emb[(size_t)tok * Dd + 2 * d2];
  float2 r;
  r.x = e2.x + sn;
  r.y = e2.y + cs;
  *(float2*)&x[(size_t)ts * Dd + 2 * d2] = r;
}

// ------------------------------------------------- MFMA flash attention
__global__ __launch_bounds__(256, 4) void attn_kernel(
    const float* __restrict__ x, const float* __restrict__ theta,
    float* __restrict__ o_out, float* __restrict__ ps_out) {
  __shared__ unsigned int qrs[Ssz * 4 + 2];  // [k][4]: f16x2 pairs, x sqrt(scale); +2 zero pad
  __shared__ unsigned int qtt[8 * QTTS];     // [d<8][pairs (k,k+1)], stride QTTS
  int blk = blockIdx.x;
  int bh = blk >> 3, split = blk & 7;
  int b = bh >> 3, h = bh & 7;
  int t = threadIdx.x;

  float th[8];
#pragma unroll
  for (int i = 0; i < 8; i++) th[i] = theta[i];

  const float* xb = x + (size_t)b * Ssz * Dd + h * 8;

#pragma unroll
  for (int i = 0; i < 4; i += 2) {
    int k0 = t * 4 + i;
    float oa[8], ob[8];
    qheads(xb + (size_t)k0 * Dd, th, oa);
    qheads(xb + (size_t)(k0 + 1) * Dd, th, ob);
    uint4 wa, wb;
    wa.x = as_u32(pkrtz(oa[0] * SQRT_PRESCALE, oa[1] * SQRT_PRESCALE));
    wa.y = as_u32(pkrtz(oa[2] * SQRT_PRESCALE, oa[3] * SQRT_PRESCALE));
    wa.z = as_u32(pkrtz(oa[4] * SQRT_PRESCALE, oa[5] * SQRT_PRESCALE));
    wa.w = as_u32(pkrtz(oa[6] * SQRT_PRESCALE, oa[7] * SQRT_PRESCALE));
    wb.x = as_u32(pkrtz(ob[0] * SQRT_PRESCALE, ob[1] * SQRT_PRESCALE));
    wb.y = as_u32(pkrtz(ob[2] * SQRT_PRESCALE, ob[3] * SQRT_PRESCALE));
    wb.z = as_u32(pkrtz(ob[4] * SQRT_PRESCALE, ob[5] * SQRT_PRESCALE));
    wb.w = as_u32(pkrtz(ob[6] * SQRT_PRESCALE, ob[7] * SQRT_PRESCALE));
    *(uint4*)&qrs[k0 * 4] = wa;
    *(uint4*)&qrs[(k0 + 1) * 4] = wb;
#pragma unroll
    for (int d = 0; d < 8; d++)
      qtt[d * QTTS + (k0 >> 1)] = as_u32(pkrtz(oa[d], ob[d]));  // unscaled
  }
  if (t == 0) { qrs[Ssz * 4] = 0; qrs[Ssz * 4 + 1] = 0; }
  __syncthreads();

  int l = t & 63, w = t >> 6;
  int g = l >> 4, rr = l & 15;
  int rt0 = split * 8 + w * 2;
  int rowA = rt0 * 16 + rr;
  int rowB = rowA + 16;
  uint2 z2; z2.x = 0; z2.y = 0;
  uint2 buA = (g < 2) ? *(const uint2*)&qrs[rowA * 4 + 2 * g] : z2;
  uint2 buB = (g < 2) ? *(const uint2*)&qrs[rowB * 4 + 2 * g] : z2;
  hh4 BrA = bc4(buA), BrB = bc4(buB);
  int aoff  = (g < 2) ? (rr * 4 + 2 * g) : (Ssz * 4);
  int astep = (g < 2) ? 64 : 0;
  int qoff  = (rr & 7) * QTTS + 2 * g;
  f4 zf = {0.f, 0.f, 0.f, 0.f};
  f4 accA0 = zf, accB0 = zf, accA1 = zf, accB1 = zf;
  float psA0 = 0.f, psB0 = 0.f, psA1 = 0.f, psB1 = 0.f;

#pragma unroll 4
  for (int kt = 0; kt < 64; kt += 2) {
    {
      uint2 au = *(const uint2*)&qrs[aoff + kt * astep];
      hh4 Ak = bc4(au);
      f4 sA = MFMA16(Ak, BrA, zf);
      f4 sB = MFMA16(Ak, BrB, zf);
      float pA0 = EXPFN(sA.x), pA1 = EXPFN(sA.y), pA2 = EXPFN(sA.z), pA3 = EXPFN(sA.w);
      float pB0 = EXPFN(sB.x), pB1 = EXPFN(sB.y), pB2 = EXPFN(sB.z), pB3 = EXPFN(sB.w);
      psA0 += (pA0 + pA1) + (pA2 + pA3);
      psB0 += (pB0 + pB1) + (pB2 + pB3);
      uint2 pbA, pbB;
      pbA.x = as_u32(pkrtz(pA0, pA1)); pbA.y = as_u32(pkrtz(pA2, pA3));
      pbB.x = as_u32(pkrtz(pB0, pB1)); pbB.y = as_u32(pkrtz(pB2, pB3));
      uint2 qt = *(const uint2*)&qtt[qoff + kt * 8];
      hh4 Aq = bc4(qt);
      accA0 = MFMA16(Aq, bc4(pbA), accA0);
      accB0 = MFMA16(Aq, bc4(pbB), accB0);
    }
    {
      uint2 au = *(const uint2*)&qrs[aoff + (kt + 1) * astep];
      hh4 Ak = bc4(au);
      f4 sA = MFMA16(Ak, BrA, zf);
      f4 sB = MFMA16(Ak, BrB, zf);
      float pA0 = EXPFN(sA.x), pA1 = EXPFN(sA.y), pA2 = EXPFN(sA.z), pA3 = EXPFN(sA.w);
      float pB0 = EXPFN(sB.x), pB1 = EXPFN(sB.y), pB2 = EXPFN(sB.z), pB3 = EXPFN(sB.w);
      psA1 += (pA0 + pA1) + (pA2 + pA3);
      psB1 += (pB0 + pB1) + (pB2 + pB3);
      uint2 pbA, pbB;
      pbA.x = as_u32(pkrtz(pA0, pA1)); pbA.y = as_u32(pkrtz(pA2, pA3));
      pbB.x = as_u32(pkrtz(pB0, pB1)); pbB.y = as_u32(pkrtz(pB2, pB3));
      uint2 qt = *(const uint2*)&qtt[qoff + (kt + 1) * 8];
      hh4 Aq = bc4(qt);
      accA1 = MFMA16(Aq, bc4(pbA), accA1);
      accB1 = MFMA16(Aq, bc4(pbB), accB1);
    }
  }
  f4 accA = accA0 + accA1;
  f4 accB = accB0 + accB1;
  float psA = psA0 + psA1, psB = psB0 + psB1;
  psA += __shfl_xor(psA, 16, 64); psA += __shfl_xor(psA, 32, 64);
  psB += __shfl_xor(psB, 16, 64); psB += __shfl_xor(psB, 32, 64);

  size_t tokA = (size_t)b * Ssz + rowA;
  size_t tokB = (size_t)b * Ssz + rowB;
  if (g < 2) {
    *(f4*)&o_out[tokA * 64 + h * 8 + 4 * g] = accA;
    *(f4*)&o_out[tokB * 64 + h * 8 + 4 * g] = accB;
  }
  if (l < 16) {
    ps_out[tokA * 8 + h] = psA;
    ps_out[tokB * 8 + h] = psB;
  }
}

// ---- tail1 (MFMA): normalize + combine-matvec + residual + LN1, in-place on x
__global__ __launch_bounds__(64) void tail1_kernel(
    float* __restrict__ x, const float* __restrict__ o_out,
    const float* __restrict__ ps_out, const float* __restrict__ Wc,
    const float* __restrict__ g1, const float* __restrict__ bb1) {
  int l = threadIdx.x & 63;
  int g = l >> 4, c = l & 15;
  int tok0 = blockIdx.x * 16;

  hh4 Bf[4][4];   // [kc][dc]
#pragma unroll
  for (int dc = 0; dc < 4; dc++)
#pragma unroll
    for (int kc = 0; kc < 4; kc++) {
      float4 wv = *(const float4*)&Wc[(size_t)(dc * 16 + c) * 64 + kc * 16 + 4 * g];
      uint2 u; u.x = as_u32(pkrtz(wv.x, wv.y)); u.y = as_u32(pkrtz(wv.z, wv.w));
      Bf[kc][dc] = bc4(u);
    }

  int tka = tok0 + c;
  hh4 Af[4];
#pragma unroll
  for (int kc = 0; kc < 4; kc++) {
    float4 o4 = *(const float4*)&o_out[(size_t)tka * 64 + kc * 16 + 4 * g];
    float inv = 1.0f / ps_out[(size_t)tka * 8 + kc * 2 + (g >> 1)];
    uint2 u;
    u.x = as_u32(pkrtz(o4.x * inv, o4.y * inv));
    u.y = as_u32(pkrtz(o4.z * inv, o4.w * inv));
    Af[kc] = bc4(u);
  }

  f4 zf = {0.f, 0.f, 0.f, 0.f};
  float yy[4][4];   // [dc][r]
#pragma unroll
  for (int dc = 0; dc < 4; dc++) {
    f4 acc = zf;
#pragma unroll
    for (int kc = 0; kc < 4; kc++) acc = MFMA16(Af[kc], Bf[kc][dc], acc);
    yy[dc][0] = acc.x; yy[dc][1] = acc.y; yy[dc][2] = acc.z; yy[dc][3] = acc.w;
  }

  float g1v[4], b1v[4];
#pragma unroll
  for (int dc = 0; dc < 4; dc++) { g1v[dc] = g1[dc * 16 + c]; b1v[dc] = bb1[dc * 16 + c]; }

#pragma unroll
  for (int r = 0; r < 4; r++) {
    int tok = tok0 + 4 * g + r;
    float rv0 = x[(size_t)tok * 64 + c]      + yy[0][r];
    float rv1 = x[(size_t)tok * 64 + 16 + c] + yy[1][r];
    float rv2 = x[(size_t)tok * 64 + 32 + c] + yy[2][r];
    float rv3 = x[(size_t)tok * 64 + 48 + c] + yy[3][r];
    float s = (rv0 + rv1) + (rv2 + rv3);
    s += __shfl_xor(s, 1, 64); s += __shfl_xor(s, 2, 64);
    s += __shfl_xor(s, 4, 64); s += __shfl_xor(s, 8, 64);
    float mu = s * (1.f / 64.f);
    float t0 = rv0 - mu, t1 = rv1 - mu, t2 = rv2 - mu, t3 = rv3 - mu;
    float q = (t0 * t0 + t1 * t1) + (t2 * t2 + t3 * t3);
    q += __shfl_xor(q, 1, 64); q += __shfl_xor(q, 2, 64);
    q += __shfl_xor(q, 4, 64); q += __shfl_xor(q, 8, 64);
    float inv = rsqrtf(q * (1.f / 64.f) + 1e-5f);
    x[(size_t)tok * 64 + c]      = t0 * inv * g1v[0] + b1v[0];
    x[(size_t)tok * 64 + 16 + c] = t1 * inv * g1v[1] + b1v[1];
    x[(size_t)tok * 64 + 32 + c] = t2 * inv * g1v[2] + b1v[2];
    x[(size_t)tok * 64 + 48 + c] = t3 * inv * g1v[3] + b1v[3];
  }
}

// ---- tail2 (MFMA): quantum FFN + residual + LN2 (in-place), pooling
// One wave per 16 tokens. MM1: H^T = W1 . z^T (8 MFMA, k=8 pad 16);
// D1 feeds MM2's B in-register. MM2: F^T = W2 . H^T (32 MFMA).
// Lane l holds token c=l&15, dims d = dc*16 + 4g + r (g=l>>4).
__global__ __launch_bounds__(64) void tail2_kernel(
    float* __restrict__ x,
    const float* __restrict__ g2, const float* __restrict__ bb2,
    const float* __restrict__ fth,
    const float* __restrict__ W1, const float* __restrict__ fb1,
    const float* __restrict__ W2, const float* __restrict__ fb2,
    float* __restrict__ partial, int do_partial) {
  int l = threadIdx.x & 63;
  int g = l >> 4, c = l & 15;
  int tok0 = blockIdx.x * 16;

  // x fragments: x4[dc][r] = x[(tok0+c)*64 + dc*16 + 4g + r]
  float4 x4[4];
#pragma unroll
  for (int dc = 0; dc < 4; dc++)
    x4[dc] = *(const float4*)&x[(size_t)(tok0 + c) * 64 + dc * 16 + 4 * g];

  // B_z: B[k=4g+jj][col=c] = cos(x1[tok c][4g+jj]) * cos(fth[4g+jj]), k<8 real
  uint2 uz; uz.x = 0; uz.y = 0;
  if (g < 2) {
    float4 thv = *(const float4*)&fth[4 * g];
    float z0 = __cosf(x4[0].x) * __cosf(thv.x);
    float z1 = __cosf(x4[0].y) * __cosf(thv.y);
    float z2 = __cosf(x4[0].z) * __cosf(thv.z);
    float z3 = __cosf(x4[0].w) * __cosf(thv.w);
    uz.x = as_u32(pkrtz(z0, z1)); uz.y = as_u32(pkrtz(z2, z3));
  }
  hh4 Bz = bc4(uz);

  f4 zf = {0.f, 0.f, 0.f, 0.f};

  // MM1 + bias + relu -> B_h fragments (8)
  hh4 Bh[8];
#pragma unroll
  for (int jc = 0; jc < 8; jc++) {
    uint2 uw; uw.x = 0; uw.y = 0;
    if (g < 2) {
      float4 wv = *(const float4*)&W1[(size_t)(jc * 16 + c) * 8 + 4 * g];
      uw.x = as_u32(pkrtz(wv.x, wv.y)); uw.y = as_u32(pkrtz(wv.z, wv.w));
    }
    f4 d1 = MFMA16(bc4(uw), Bz, zf);   // H^T[jc*16+4g+r][tok c]
    float4 b1v = *(const float4*)&fb1[jc * 16 + 4 * g];
    float h0 = fmaxf(d1.x + b1v.x, 0.f);
    float h1 = fmaxf(d1.y + b1v.y, 0.f);
    float h2 = fmaxf(d1.z + b1v.z, 0.f);
    float h3 = fmaxf(d1.w + b1v.w, 0.f);
    uint2 uh;
    uh.x = as_u32(pkrtz(h0, h1)); uh.y = as_u32(pkrtz(h2, h3));
    Bh[jc] = bc4(uh);
  }

  // MM2: F^T[dc*16+4g+r][tok c] = sum_kc W2-tile . Bh[kc]
  float ff[4][4];   // [dc][r]
#pragma unroll
  for (int dc = 0; dc < 4; dc++) {
    f4 acc = zf;
#pragma unroll
    for (int kc = 0; kc < 8; kc++) {
      float4 wv = *(const float4*)&W2[(size_t)(dc * 16 + c) * 128 + kc * 16 + 4 * g];
      uint2 uw;
      uw.x = as_u32(pkrtz(wv.x, wv.y)); uw.y = as_u32(pkrtz(wv.z, wv.w));
      acc = MFMA16(bc4(uw), Bh[kc], acc);
    }
    ff[dc][0] = acc.x; ff[dc][1] = acc.y; ff[dc][2] = acc.z; ff[dc][3] = acc.w;
  }

  // residual + LN2 (reduce over d = across dc,r in-lane + g-groups via xor 16,32)
  float r2[4][4];
  float s = 0.f;
#pragma unroll
  for (int dc = 0; dc < 4; dc++) {
    float4 b2v = *(const float4*)&fb2[dc * 16 + 4 * g];
    r2[dc][0] = x4[dc].x + ff[dc][0] + b2v.x;
    r2[dc][1] = x4[dc].y + ff[dc][1] + b2v.y;
    r2[dc][2] = x4[dc].z + ff[dc][2] + b2v.z;
    r2[dc][3] = x4[dc].w + ff[dc][3] + b2v.w;
    s += (r2[dc][0] + r2[dc][1]) + (r2[dc][2] + r2[dc][3]);
  }
  s += __shfl_xor(s, 16, 64); s += __shfl_xor(s, 32, 64);
  float mu = s * (1.f / 64.f);
  float q = 0.f;
#pragma unroll
  for (int dc = 0; dc < 4; dc++) {
#pragma unroll
    for (int r = 0; r < 4; r++) { r2[dc][r] -= mu; q += r2[dc][r] * r2[dc][r]; }
  }
  q += __shfl_xor(q, 16, 64); q += __shfl_xor(q, 32, 64);
  float inv = rsqrtf(q * (1.f / 64.f) + 1e-5f);

  float xo[4][4];
#pragma unroll
  for (int dc = 0; dc < 4; dc++) {
    float4 gv = *(const float4*)&g2[dc * 16 + 4 * g];
    float4 bv = *(const float4*)&bb2[dc * 16 + 4 * g];
    xo[dc][0] = r2[dc][0] * inv * gv.x + bv.x;
    xo[dc][1] = r2[dc][1] * inv * gv.y + bv.y;
    xo[dc][2] = r2[dc][2] * inv * gv.z + bv.z;
    xo[dc][3] = r2[dc][3] * inv * gv.w + bv.w;
    float4 o4;
    o4.x = xo[dc][0]; o4.y = xo[dc][1]; o4.z = xo[dc][2]; o4.w = xo[dc][3];
    *(float4*)&x[(size_t)(tok0 + c) * 64 + dc * 16 + 4 * g] = o4;
  }

  if (do_partial) {
    // pool over the 16 tokens: xor-reduce across c bits
#pragma unroll
    for (int dc = 0; dc < 4; dc++)
#pragma unroll
      for (int r = 0; r < 4; r++) {
        float p = xo[dc][r];
        p += __shfl_xor(p, 1, 64); p += __shfl_xor(p, 2, 64);
        p += __shfl_xor(p, 4, 64); p += __shfl_xor(p, 8, 64);
        xo[dc][r] = p;
      }
    if (c == 0) {
#pragma unroll
      for (int dc = 0; dc < 4; dc++) {
        float4 o4;
        o4.x = xo[dc][0]; o4.y = xo[dc][1]; o4.z = xo[dc][2]; o4.w = xo[dc][3];
        *(float4*)&partial[(size_t)blockIdx.x * 64 + dc * 16 + 4 * g] = o4;
      }
    }
  }
}

// ------------------------------------------------ pooled mean + MLP head
__global__ __launch_bounds__(128) void head_kernel(
    const float* __restrict__ partial,   // [1024][64]
    const float* eW1, const float* eb1, const float* eW2, const float* eb2,
    const float* eW3, const float* eb3, const float* dW1, const float* db1v,
    const float* dW2, const float* db2v, const float* dW3, const float* db3v,
    const float* cW, const float* cb, float* __restrict__ out) {
  __shared__ float bufP[64];
  __shared__ float bufA[128];
  __shared__ float bufB[128];
  int b = blockIdx.x, t = threadIdx.x;
  if (t < 64) {
    float s = 0.f;
    for (int c = 0; c < 64; ++c) s += partial[(size_t)(b * 64 + c) * 64 + t];
    bufP[t] = s * (1.f / 1024.f);
  }
  __syncthreads();
  {
    float v = eb1[t];
    for (int d = 0; d < 64; d++) v = fmaf(bufP[d], eW1[t * 64 + d], v);
    bufA[t] = fmaxf(v, 0.f);
  }
  __syncthreads();
  if (t < 64) {
    float v = eb2[t];
    for (int j = 0; j < 128; j++) v = fmaf(bufA[j], eW2[t * 128 + j], v);
    bufB[t] = fmaxf(v, 0.f);
  }
  __syncthreads();
  if (t < 32) {
    float v = eb3[t];
    for (int d = 0; d < 64; d++) v = fmaf(bufB[d], eW3[t * 64 + d], v);
    bufA[t] = v;   // latent in bufA[0..31]
  }
  __syncthreads();
  if (t < 64) {
    float v = db1v[t];
    for (int k = 0; k < 32; k++) v = fmaf(bufA[k], dW1[t * 32 + k], v);
    bufB[t] = fmaxf(v, 0.f);
  }
  __syncthreads();
  {
    float v = db2v[t];
    for (int k = 0; k < 64; k++) v = fmaf(bufB[k], dW2[t * 64 + k], v);
    bufA[t] = fmaxf(v, 0.f);
  }
  __syncthreads();
  if (t < 64) {
    float v = db3v[t];
    for (int j = 0; j < 128; j++) v = fmaf(bufA[j], dW3[t * 128 + j], v);
    bufB[t] = v;
  }
  __syncthreads();
  if (t < 10) {
    float v = cb[t];
    for (int d = 0; d < 64; d++) v = fmaf(bufB[d], cW[t * 64 + d], v);
    out[b * 10 + t] = v;
  }
}

extern "C" void kernel_launch(void* const* d_in, const int* in_sizes, int n_in,
                              void* d_out, int out_size, void* d_ws, size_t ws_size,
                              hipStream_t stream) {
  const int*   tokens     = (const int*)d_in[0];
  const float* emb        = (const float*)d_in[1];
  const float* attn_theta = (const float*)d_in[2];
  const float* combine_W  = (const float*)d_in[3];
  const float* ln1_g      = (const float*)d_in[4];
  const float* ln1_b      = (const float*)d_in[5];
  const float* ln2_g      = (const float*)d_in[6];
  const float* ln2_b      = (const float*)d_in[7];
  const float* ffn_theta  = (const float*)d_in[8];
  const float* ffn_W1     = (const float*)d_in[9];
  const float* ffn_b1     = (const float*)d_in[10];
  const float* ffn_W2     = (const float*)d_in[11];
  const float* ffn_b2     = (const float*)d_in[12];
  const float* enc_W1 = (const float*)d_in[13]; const float* enc_b1 = (const float*)d_in[14];
  const float* enc_W2 = (const float*)d_in[15]; const float* enc_b2 = (const float*)d_in[16];
  const float* enc_W3 = (const float*)d_in[17]; const float* enc_b3 = (const float*)d_in[18];
  const float* dec_W1 = (const float*)d_in[19]; const float* dec_b1 = (const float*)d_in[20];
  const float* dec_W2 = (const float*)d_in[21]; const float* dec_b2 = (const float*)d_in[22];
  const float* dec_W3 = (const float*)d_in[23]; const float* dec_b3 = (const float*)d_in[24];
  const float* cls_W  = (const float*)d_in[25]; const float* cls_b  = (const float*)d_in[26];

  float* x       = (float*)d_ws;                      // 1M floats
  float* o_out   = x + (size_t)TOKENS * 64;           // 1M floats
  float* ps_out  = o_out + (size_t)TOKENS * 64;       // 128K floats
  float* partial = ps_out + (size_t)TOKENS * 8;       // 64K floats
  float* out     = (float*)d_out;

  embed_kernel<<<(TOKENS * 32 + 255) / 256, 256, 0, stream>>>(tokens, emb, x);
  for (int l = 0; l < 2; ++l) {
    attn_kernel<<<128 * 8, 256, 0, stream>>>(x, attn_theta + l * 8, o_out, ps_out);
    tail1_kernel<<<TOKENS / 16, 64, 0, stream>>>(
        x, o_out, ps_out, combine_W + l * 4096, ln1_g + l * 64, ln1_b + l * 64);
    tail2_kernel<<<TOKENS / 16, 64, 0, stream>>>(
        x, ln2_g + l * 64, ln2_b + l * 64,
        ffn_theta + l * 8, ffn_W1 + l * 1024, ffn_b1 + l * 128,
        ffn_W2 + l * 8192, ffn_b2 + l * 64, partial, (l == 1) ? 1 : 0);
  }
  head_kernel<<<16, 128, 0, stream>>>(partial, enc_W1, enc_b1, enc_W2, enc_b2,
                                      enc_W3, enc_b3, dec_W1, dec_b1, dec_W2,
                                      dec_b2, dec_W3, dec_b3, cls_W, cls_b, out);
}

// Round 12
// 89.914 us; speedup vs baseline: 1.7293x; 1.1372x over previous
//
#include <hip/hip_runtime.h>
#include <math.h>

typedef _Float16 h2 __attribute__((ext_vector_type(2)));
typedef __fp16 hh4 __attribute__((ext_vector_type(4)));
typedef float f4 __attribute__((ext_vector_type(4)));

#define Bsz 16
#define Ssz 1024
#define TOKENS (Bsz * Ssz)   // 16384
#define Dd 64
#define Hh 8
#define QTTS 520             // qtt LDS row stride (words)

#if __has_builtin(__builtin_amdgcn_exp2f)
  #define EXPFN(x) __builtin_amdgcn_exp2f(x)
  #define SQRT_PRESCALE 0.7141921f     // sqrt((1/sqrt(8)) * log2(e))
#else
  #define EXPFN(x) __expf(x)
  #define SQRT_PRESCALE 0.5946036f     // sqrt(1/sqrt(8))
#endif

#if __has_builtin(__builtin_amdgcn_mfma_f32_16x16x16_f16)
  #define MFMA16(a, b, c) __builtin_amdgcn_mfma_f32_16x16x16_f16(a, b, c, 0, 0, 0)
#else
  #define MFMA16(a, b, c) __builtin_amdgcn_mfma_f32_16x16x16f16(a, b, c, 0, 0, 0)
#endif

__device__ __forceinline__ h2 pkrtz(float a, float b) {
#if __has_builtin(__builtin_amdgcn_cvt_pkrtz)
  return __builtin_bit_cast(h2, __builtin_amdgcn_cvt_pkrtz(a, b));
#else
  h2 r; r.x = (_Float16)a; r.y = (_Float16)b; return r;
#endif
}
__device__ __forceinline__ unsigned int as_u32(h2 v) {
  return __builtin_bit_cast(unsigned int, v);
}
__device__ __forceinline__ hh4 bc4(uint2 u) {
  return __builtin_bit_cast(hh4, u);
}

// quantum head q-vector for one token/head
__device__ __forceinline__ void qheads(const float* __restrict__ xp,
                                       const float* th, float* o) {
  float4 v0 = *(const float4*)(xp);
  float4 v1 = *(const float4*)(xp + 4);
  float c0 = __cosf(v0.x + th[0]), c1 = __cosf(v0.y + th[1]);
  float c2 = __cosf(v0.z + th[2]), c3 = __cosf(v0.w + th[3]);
  float c4 = __cosf(v1.x + th[4]), c5 = __cosf(v1.y + th[5]);
  float c6 = __cosf(v1.z + th[6]), c7 = __cosf(v1.w + th[7]);
  float cp = c0;
  cp *= c1; o[1] = cp; cp *= c2; o[2] = cp; cp *= c3; o[3] = cp;
  cp *= c4; o[4] = cp; cp *= c5; o[5] = cp; cp *= c6; o[6] = cp;
  cp *= c7; o[7] = cp;
  o[0] = c1 * c2 * c3 * c4 * c5 * c6 * c7;
}

// ---------------------------------------------------------------- embed + pos
__global__ __launch_bounds__(256) void embed_kernel(
    const int* __restrict__ tokens, const float* __restrict__ emb,
    float* __restrict__ x) {
  int gid = blockIdx.x * 256 + threadIdx.x;   // 0 .. TOKENS*32-1
  if (gid >= TOKENS * 32) return;
  int d2 = gid & 31;
  int ts = gid >> 5;
  int s  = ts & (Ssz - 1);
  int tok = tokens[ts];
  float freq = __expf((float)(2 * d2) * (-0.14391156831f));
  float ang = (float)s * freq;
  float sn, cs;
  __sincosf(ang, &sn, &cs);
  float2 e2 = *(const float2*)&emb[(size_t)tok * Dd + 2 * d2];
  float2 r;
  r.x = e2.x + sn;
  r.y = e2.y + cs;
  *(float2*)&x[(size_t)ts * Dd + 2 * d2] = r;
}

// ------------------------------------------------- MFMA flash attention
// qtt row 8 = ones -> PV MFMA D-row 8 yields the softmax denominator free.
__global__ __launch_bounds__(256, 4) void attn_kernel(
    const float* __restrict__ x, const float* __restrict__ theta,
    float* __restrict__ o_out, float* __restrict__ ps_out) {
  __shared__ unsigned int qrs[Ssz * 4 + 2];  // [k][4]: f16x2 pairs, x sqrt(scale); +2 zero pad
  __shared__ unsigned int qtt[9 * QTTS];     // [d<8 | ones][pairs (k,k+1)]
  int blk = blockIdx.x;
  int bh = blk >> 3, split = blk & 7;
  int b = bh >> 3, h = bh & 7;
  int t = threadIdx.x;

  float th[8];
#pragma unroll
  for (int i = 0; i < 8; i++) th[i] = theta[i];

  const float* xb = x + (size_t)b * Ssz * Dd + h * 8;

#pragma unroll
  for (int i = 0; i < 4; i += 2) {
    int k0 = t * 4 + i;
    float oa[8], ob[8];
    qheads(xb + (size_t)k0 * Dd, th, oa);
    qheads(xb + (size_t)(k0 + 1) * Dd, th, ob);
    uint4 wa, wb;
    wa.x = as_u32(pkrtz(oa[0] * SQRT_PRESCALE, oa[1] * SQRT_PRESCALE));
    wa.y = as_u32(pkrtz(oa[2] * SQRT_PRESCALE, oa[3] * SQRT_PRESCALE));
    wa.z = as_u32(pkrtz(oa[4] * SQRT_PRESCALE, oa[5] * SQRT_PRESCALE));
    wa.w = as_u32(pkrtz(oa[6] * SQRT_PRESCALE, oa[7] * SQRT_PRESCALE));
    wb.x = as_u32(pkrtz(ob[0] * SQRT_PRESCALE, ob[1] * SQRT_PRESCALE));
    wb.y = as_u32(pkrtz(ob[2] * SQRT_PRESCALE, ob[3] * SQRT_PRESCALE));
    wb.z = as_u32(pkrtz(ob[4] * SQRT_PRESCALE, ob[5] * SQRT_PRESCALE));
    wb.w = as_u32(pkrtz(ob[6] * SQRT_PRESCALE, ob[7] * SQRT_PRESCALE));
    *(uint4*)&qrs[k0 * 4] = wa;
    *(uint4*)&qrs[(k0 + 1) * 4] = wb;
#pragma unroll
    for (int d = 0; d < 8; d++)
      qtt[d * QTTS + (k0 >> 1)] = as_u32(pkrtz(oa[d], ob[d]));  // unscaled
  }
  for (int j = 8 * QTTS + t; j < 9 * QTTS; j += 256) qtt[j] = 0x3C003C00u;  // ones row
  if (t == 0) { qrs[Ssz * 4] = 0; qrs[Ssz * 4 + 1] = 0; }
  __syncthreads();

  int l = t & 63, w = t >> 6;
  int g = l >> 4, rr = l & 15;
  int rt0 = split * 8 + w * 2;
  int rowA = rt0 * 16 + rr;
  int rowB = rowA + 16;
  uint2 z2; z2.x = 0; z2.y = 0;
  uint2 buA = (g < 2) ? *(const uint2*)&qrs[rowA * 4 + 2 * g] : z2;
  uint2 buB = (g < 2) ? *(const uint2*)&qrs[rowB * 4 + 2 * g] : z2;
  hh4 BrA = bc4(buA), BrB = bc4(buB);
  int aoff  = (g < 2) ? (rr * 4 + 2 * g) : (Ssz * 4);
  int astep = (g < 2) ? 64 : 0;
  int qrow  = (rr >= 8) ? 8 : rr;       // rows 8-15 read the ones row (8) — rows 9-15 garbage, discarded
  int qoff  = qrow * QTTS + 2 * g;
  f4 zf = {0.f, 0.f, 0.f, 0.f};
  f4 accA0 = zf, accB0 = zf, accA1 = zf, accB1 = zf;

#pragma unroll 4
  for (int kt = 0; kt < 64; kt += 2) {
    {
      uint2 au = *(const uint2*)&qrs[aoff + kt * astep];
      hh4 Ak = bc4(au);
      f4 sA = MFMA16(Ak, BrA, zf);
      f4 sB = MFMA16(Ak, BrB, zf);
      float pA0 = EXPFN(sA.x), pA1 = EXPFN(sA.y), pA2 = EXPFN(sA.z), pA3 = EXPFN(sA.w);
      float pB0 = EXPFN(sB.x), pB1 = EXPFN(sB.y), pB2 = EXPFN(sB.z), pB3 = EXPFN(sB.w);
      uint2 pbA, pbB;
      pbA.x = as_u32(pkrtz(pA0, pA1)); pbA.y = as_u32(pkrtz(pA2, pA3));
      pbB.x = as_u32(pkrtz(pB0, pB1)); pbB.y = as_u32(pkrtz(pB2, pB3));
      uint2 qt = *(const uint2*)&qtt[qoff + kt * 8];
      hh4 Aq = bc4(qt);
      accA0 = MFMA16(Aq, bc4(pbA), accA0);
      accB0 = MFMA16(Aq, bc4(pbB), accB0);
    }
    {
      uint2 au = *(const uint2*)&qrs[aoff + (kt + 1) * astep];
      hh4 Ak = bc4(au);
      f4 sA = MFMA16(Ak, BrA, zf);
      f4 sB = MFMA16(Ak, BrB, zf);
      float pA0 = EXPFN(sA.x), pA1 = EXPFN(sA.y), pA2 = EXPFN(sA.z), pA3 = EXPFN(sA.w);
      float pB0 = EXPFN(sB.x), pB1 = EXPFN(sB.y), pB2 = EXPFN(sB.z), pB3 = EXPFN(sB.w);
      uint2 pbA, pbB;
      pbA.x = as_u32(pkrtz(pA0, pA1)); pbA.y = as_u32(pkrtz(pA2, pA3));
      pbB.x = as_u32(pkrtz(pB0, pB1)); pbB.y = as_u32(pkrtz(pB2, pB3));
      uint2 qt = *(const uint2*)&qtt[qoff + (kt + 1) * 8];
      hh4 Aq = bc4(qt);
      accA1 = MFMA16(Aq, bc4(pbA), accA1);
      accB1 = MFMA16(Aq, bc4(pbB), accB1);
    }
  }
  f4 accA = accA0 + accA1;
  f4 accB = accB0 + accB1;

  size_t tokA = (size_t)b * Ssz + rowA;
  size_t tokB = (size_t)b * Ssz + rowB;
  if (g < 2) {                     // D rows 0-7: O^T
    *(f4*)&o_out[tokA * 64 + h * 8 + 4 * g] = accA;
    *(f4*)&o_out[tokB * 64 + h * 8 + 4 * g] = accB;
  } else if (g == 2) {             // D row 8 (reg .x): softmax denominator
    ps_out[tokA * 8 + h] = accA.x;
    ps_out[tokB * 8 + h] = accB.x;
  }
}

// ---- fused tail (MFMA): combine+LN1 -> xbuf (LDS) -> FFN+LN2, pooling.
// One wave per 16 tokens, no barriers (single-wave block).
__global__ __launch_bounds__(64) void tail_kernel(
    float* __restrict__ x, const float* __restrict__ o_out,
    const float* __restrict__ ps_out, const float* __restrict__ Wc,
    const float* __restrict__ g1, const float* __restrict__ bb1,
    const float* __restrict__ g2, const float* __restrict__ bb2,
    const float* __restrict__ fth,
    const float* __restrict__ W1, const float* __restrict__ fb1,
    const float* __restrict__ W2, const float* __restrict__ fb2,
    float* __restrict__ partial, int do_partial) {
  __shared__ float xbuf[16][68];   // x1: [token][dim], +4 pad
  int l = threadIdx.x & 63;
  int g = l >> 4, c = l & 15;
  int tok0 = blockIdx.x * 16;
  f4 zf = {0.f, 0.f, 0.f, 0.f};

  // ---------- phase 1: normalize + combine-matvec + residual + LN1 -> xbuf
  {
    hh4 Bf[4][4];   // [kc][dc]
#pragma unroll
    for (int dc = 0; dc < 4; dc++)
#pragma unroll
      for (int kc = 0; kc < 4; kc++) {
        float4 wv = *(const float4*)&Wc[(size_t)(dc * 16 + c) * 64 + kc * 16 + 4 * g];
        uint2 u; u.x = as_u32(pkrtz(wv.x, wv.y)); u.y = as_u32(pkrtz(wv.z, wv.w));
        Bf[kc][dc] = bc4(u);
      }
    int tka = tok0 + c;
    hh4 Af[4];
#pragma unroll
    for (int kc = 0; kc < 4; kc++) {
      float4 o4 = *(const float4*)&o_out[(size_t)tka * 64 + kc * 16 + 4 * g];
      float inv = 1.0f / ps_out[(size_t)tka * 8 + kc * 2 + (g >> 1)];
      uint2 u;
      u.x = as_u32(pkrtz(o4.x * inv, o4.y * inv));
      u.y = as_u32(pkrtz(o4.z * inv, o4.w * inv));
      Af[kc] = bc4(u);
    }
    float yy[4][4];   // [dc][r]
#pragma unroll
    for (int dc = 0; dc < 4; dc++) {
      f4 acc = zf;
#pragma unroll
      for (int kc = 0; kc < 4; kc++) acc = MFMA16(Af[kc], Bf[kc][dc], acc);
      yy[dc][0] = acc.x; yy[dc][1] = acc.y; yy[dc][2] = acc.z; yy[dc][3] = acc.w;
    }
    float g1v[4], b1v[4];
#pragma unroll
    for (int dc = 0; dc < 4; dc++) { g1v[dc] = g1[dc * 16 + c]; b1v[dc] = bb1[dc * 16 + c]; }
#pragma unroll
    for (int r = 0; r < 4; r++) {
      int tok = tok0 + 4 * g + r;
      float rv0 = x[(size_t)tok * 64 + c]      + yy[0][r];
      float rv1 = x[(size_t)tok * 64 + 16 + c] + yy[1][r];
      float rv2 = x[(size_t)tok * 64 + 32 + c] + yy[2][r];
      float rv3 = x[(size_t)tok * 64 + 48 + c] + yy[3][r];
      float s = (rv0 + rv1) + (rv2 + rv3);
      s += __shfl_xor(s, 1, 64); s += __shfl_xor(s, 2, 64);
      s += __shfl_xor(s, 4, 64); s += __shfl_xor(s, 8, 64);
      float mu = s * (1.f / 64.f);
      float t0 = rv0 - mu, t1 = rv1 - mu, t2 = rv2 - mu, t3 = rv3 - mu;
      float q = (t0 * t0 + t1 * t1) + (t2 * t2 + t3 * t3);
      q += __shfl_xor(q, 1, 64); q += __shfl_xor(q, 2, 64);
      q += __shfl_xor(q, 4, 64); q += __shfl_xor(q, 8, 64);
      float inv = rsqrtf(q * (1.f / 64.f) + 1e-5f);
      int tk = 4 * g + r;
      xbuf[tk][c]      = t0 * inv * g1v[0] + b1v[0];
      xbuf[tk][16 + c] = t1 * inv * g1v[1] + b1v[1];
      xbuf[tk][32 + c] = t2 * inv * g1v[2] + b1v[2];
      xbuf[tk][48 + c] = t3 * inv * g1v[3] + b1v[3];
    }
  }
  // single wave: LDS writes above are ordered before reads below

  // ---------- phase 2: quantum FFN + residual + LN2 -> x, pooling
  float4 x4[4];
#pragma unroll
  for (int dc = 0; dc < 4; dc++)
    x4[dc] = *(const float4*)&xbuf[c][dc * 16 + 4 * g];

  uint2 uz; uz.x = 0; uz.y = 0;
  if (g < 2) {
    float4 thv = *(const float4*)&fth[4 * g];
    float z0 = __cosf(x4[0].x) * __cosf(thv.x);
    float z1 = __cosf(x4[0].y) * __cosf(thv.y);
    float z2 = __cosf(x4[0].z) * __cosf(thv.z);
    float z3 = __cosf(x4[0].w) * __cosf(thv.w);
    uz.x = as_u32(pkrtz(z0, z1)); uz.y = as_u32(pkrtz(z2, z3));
  }
  hh4 Bz = bc4(uz);

  hh4 Bh[8];
#pragma unroll
  for (int jc = 0; jc < 8; jc++) {
    uint2 uw; uw.x = 0; uw.y = 0;
    if (g < 2) {
      float4 wv = *(const float4*)&W1[(size_t)(jc * 16 + c) * 8 + 4 * g];
      uw.x = as_u32(pkrtz(wv.x, wv.y)); uw.y = as_u32(pkrtz(wv.z, wv.w));
    }
    f4 d1 = MFMA16(bc4(uw), Bz, zf);
    float4 b1v = *(const float4*)&fb1[jc * 16 + 4 * g];
    float h0 = fmaxf(d1.x + b1v.x, 0.f);
    float h1 = fmaxf(d1.y + b1v.y, 0.f);
    float h2 = fmaxf(d1.z + b1v.z, 0.f);
    float h3 = fmaxf(d1.w + b1v.w, 0.f);
    uint2 uh;
    uh.x = as_u32(pkrtz(h0, h1)); uh.y = as_u32(pkrtz(h2, h3));
    Bh[jc] = bc4(uh);
  }

  float ff[4][4];
#pragma unroll
  for (int dc = 0; dc < 4; dc++) {
    f4 acc = zf;
#pragma unroll
    for (int kc = 0; kc < 8; kc++) {
      float4 wv = *(const float4*)&W2[(size_t)(dc * 16 + c) * 128 + kc * 16 + 4 * g];
      uint2 uw;
      uw.x = as_u32(pkrtz(wv.x, wv.y)); uw.y = as_u32(pkrtz(wv.z, wv.w));
      acc = MFMA16(bc4(uw), Bh[kc], acc);
    }
    ff[dc][0] = acc.x; ff[dc][1] = acc.y; ff[dc][2] = acc.z; ff[dc][3] = acc.w;
  }

  float r2[4][4];
  float s = 0.f;
#pragma unroll
  for (int dc = 0; dc < 4; dc++) {
    float4 b2v = *(const float4*)&fb2[dc * 16 + 4 * g];
    r2[dc][0] = x4[dc].x + ff[dc][0] + b2v.x;
    r2[dc][1] = x4[dc].y + ff[dc][1] + b2v.y;
    r2[dc][2] = x4[dc].z + ff[dc][2] + b2v.z;
    r2[dc][3] = x4[dc].w + ff[dc][3] + b2v.w;
    s += (r2[dc][0] + r2[dc][1]) + (r2[dc][2] + r2[dc][3]);
  }
  s += __shfl_xor(s, 16, 64); s += __shfl_xor(s, 32, 64);
  float mu = s * (1.f / 64.f);
  float q = 0.f;
#pragma unroll
  for (int dc = 0; dc < 4; dc++) {
#pragma unroll
    for (int r = 0; r < 4; r++) { r2[dc][r] -= mu; q += r2[dc][r] * r2[dc][r]; }
  }
  q += __shfl_xor(q, 16, 64); q += __shfl_xor(q, 32, 64);
  float inv = rsqrtf(q * (1.f / 64.f) + 1e-5f);

  float xo[4][4];
#pragma unroll
  for (int dc = 0; dc < 4; dc++) {
    float4 gv = *(const float4*)&g2[dc * 16 + 4 * g];
    float4 bv = *(const float4*)&bb2[dc * 16 + 4 * g];
    xo[dc][0] = r2[dc][0] * inv * gv.x + bv.x;
    xo[dc][1] = r2[dc][1] * inv * gv.y + bv.y;
    xo[dc][2] = r2[dc][2] * inv * gv.z + bv.z;
    xo[dc][3] = r2[dc][3] * inv * gv.w + bv.w;
    float4 o4;
    o4.x = xo[dc][0]; o4.y = xo[dc][1]; o4.z = xo[dc][2]; o4.w = xo[dc][3];
    *(float4*)&x[(size_t)(tok0 + c) * 64 + dc * 16 + 4 * g] = o4;
  }

  if (do_partial) {
#pragma unroll
    for (int dc = 0; dc < 4; dc++)
#pragma unroll
      for (int r = 0; r < 4; r++) {
        float p = xo[dc][r];
        p += __shfl_xor(p, 1, 64); p += __shfl_xor(p, 2, 64);
        p += __shfl_xor(p, 4, 64); p += __shfl_xor(p, 8, 64);
        xo[dc][r] = p;
      }
    if (c == 0) {
#pragma unroll
      for (int dc = 0; dc < 4; dc++) {
        float4 o4;
        o4.x = xo[dc][0]; o4.y = xo[dc][1]; o4.z = xo[dc][2]; o4.w = xo[dc][3];
        *(float4*)&partial[(size_t)blockIdx.x * 64 + dc * 16 + 4 * g] = o4;
      }
    }
  }
}

// ------------------------------------------------ pooled mean + MLP head
__global__ __launch_bounds__(128) void head_kernel(
    const float* __restrict__ partial,   // [1024][64]
    const float* eW1, const float* eb1, const float* eW2, const float* eb2,
    const float* eW3, const float* eb3, const float* dW1, const float* db1v,
    const float* dW2, const float* db2v, const float* dW3, const float* db3v,
    const float* cW, const float* cb, float* __restrict__ out) {
  __shared__ float bufP[64];
  __shared__ float bufA[128];
  __shared__ float bufB[128];
  int b = blockIdx.x, t = threadIdx.x;
  if (t < 64) {
    float s = 0.f;
    for (int c = 0; c < 64; ++c) s += partial[(size_t)(b * 64 + c) * 64 + t];
    bufP[t] = s * (1.f / 1024.f);
  }
  __syncthreads();
  {
    float v = eb1[t];
    for (int d = 0; d < 64; d++) v = fmaf(bufP[d], eW1[t * 64 + d], v);
    bufA[t] = fmaxf(v, 0.f);
  }
  __syncthreads();
  if (t < 64) {
    float v = eb2[t];
    for (int j = 0; j < 128; j++) v = fmaf(bufA[j], eW2[t * 128 + j], v);
    bufB[t] = fmaxf(v, 0.f);
  }
  __syncthreads();
  if (t < 32) {
    float v = eb3[t];
    for (int d = 0; d < 64; d++) v = fmaf(bufB[d], eW3[t * 64 + d], v);
    bufA[t] = v;   // latent in bufA[0..31]
  }
  __syncthreads();
  if (t < 64) {
    float v = db1v[t];
    for (int k = 0; k < 32; k++) v = fmaf(bufA[k], dW1[t * 32 + k], v);
    bufB[t] = fmaxf(v, 0.f);
  }
  __syncthreads();
  {
    float v = db2v[t];
    for (int k = 0; k < 64; k++) v = fmaf(bufB[k], dW2[t * 64 + k], v);
    bufA[t] = fmaxf(v, 0.f);
  }
  __syncthreads();
  if (t < 64) {
    float v = db3v[t];
    for (int j = 0; j < 128; j++) v = fmaf(bufA[j], dW3[t * 128 + j], v);
    bufB[t] = v;
  }
  __syncthreads();
  if (t < 10) {
    float v = cb[t];
    for (int d = 0; d < 64; d++) v = fmaf(bufB[d], cW[t * 64 + d], v);
    out[b * 10 + t] = v;
  }
}

extern "C" void kernel_launch(void* const* d_in, const int* in_sizes, int n_in,
                              void* d_out, int out_size, void* d_ws, size_t ws_size,
                              hipStream_t stream) {
  const int*   tokens     = (const int*)d_in[0];
  const float* emb        = (const float*)d_in[1];
  const float* attn_theta = (const float*)d_in[2];
  const float* combine_W  = (const float*)d_in[3];
  const float* ln1_g      = (const float*)d_in[4];
  const float* ln1_b      = (const float*)d_in[5];
  const float* ln2_g      = (const float*)d_in[6];
  const float* ln2_b      = (const float*)d_in[7];
  const float* ffn_theta  = (const float*)d_in[8];
  const float* ffn_W1     = (const float*)d_in[9];
  const float* ffn_b1     = (const float*)d_in[10];
  const float* ffn_W2     = (const float*)d_in[11];
  const float* ffn_b2     = (const float*)d_in[12];
  const float* enc_W1 = (const float*)d_in[13]; const float* enc_b1 = (const float*)d_in[14];
  const float* enc_W2 = (const float*)d_in[15]; const float* enc_b2 = (const float*)d_in[16];
  const float* enc_W3 = (const float*)d_in[17]; const float* enc_b3 = (const float*)d_in[18];
  const float* dec_W1 = (const float*)d_in[19]; const float* dec_b1 = (const float*)d_in[20];
  const float* dec_W2 = (const float*)d_in[21]; const float* dec_b2 = (const float*)d_in[22];
  const float* dec_W3 = (const float*)d_in[23]; const float* dec_b3 = (const float*)d_in[24];
  const float* cls_W  = (const float*)d_in[25]; const float* cls_b  = (const float*)d_in[26];

  float* x       = (float*)d_ws;                      // 1M floats
  float* o_out   = x + (size_t)TOKENS * 64;           // 1M floats
  float* ps_out  = o_out + (size_t)TOKENS * 64;       // 128K floats
  float* partial = ps_out + (size_t)TOKENS * 8;       // 64K floats
  float* out     = (float*)d_out;

  embed_kernel<<<(TOKENS * 32 + 255) / 256, 256, 0, stream>>>(tokens, emb, x);
  for (int l = 0; l < 2; ++l) {
    attn_kernel<<<128 * 8, 256, 0, stream>>>(x, attn_theta + l * 8, o_out, ps_out);
    tail_kernel<<<TOKENS / 16, 64, 0, stream>>>(
        x, o_out, ps_out, combine_W + l * 4096,
        ln1_g + l * 64, ln1_b + l * 64, ln2_g + l * 64, ln2_b + l * 64,
        ffn_theta + l * 8, ffn_W1 + l * 1024, ffn_b1 + l * 128,
        ffn_W2 + l * 8192, ffn_b2 + l * 64, partial, (l == 1) ? 1 : 0);
  }
  head_kernel<<<16, 128, 0, stream>>>(partial, enc_W1, enc_b1, enc_W2, enc_b2,
                                      enc_W3, enc_b3, dec_W1, dec_b1, dec_W2,
                                      dec_b2, dec_W3, dec_b3, cls_W, cls_b, out);
}